// Round 2
// 1126.409 us; speedup vs baseline: 1.2568x; 1.2568x over previous
//
#include <hip/hip_runtime.h>
#include <math.h>

#define BB 4096
#define HH 1024
#define RR 10
#define MIDD 512
#define D3 3072

typedef __bf16 bf16x8 __attribute__((ext_vector_type(8)));
typedef __bf16 bf16x4 __attribute__((ext_vector_type(4)));
typedef float f32x4 __attribute__((ext_vector_type(4)));

// ---------------- reduction helpers ----------------
__device__ __forceinline__ float waveSum(float v){
#pragma unroll
  for(int o=32;o>0;o>>=1) v += __shfl_down(v,o,64);
  return v;
}
__device__ __forceinline__ float blockSum256(float v, float* sc){
  v = waveSum(v);
  __syncthreads();
  if((threadIdx.x & 63)==0) sc[threadIdx.x>>6] = v;
  __syncthreads();
  return sc[0]+sc[1]+sc[2]+sc[3];
}
__device__ __forceinline__ float gelu_f(float x){
  return 0.5f*x*(1.0f+erff(x*0.70710678118654752f));
}
__device__ __forceinline__ void gl_lds16(const void* g, void* lds){
  __builtin_amdgcn_global_load_lds((const __attribute__((address_space(1))) unsigned int*)g,
                                   (__attribute__((address_space(3))) unsigned int*)lds,
                                   16, 0, 0);
}

// ---------- weight convert: 5 fp32 matrices -> bf16, one launch -------------
__global__ void convw_k(const float* __restrict__ s0, __bf16* __restrict__ d0, int n0,
                        const float* __restrict__ s1, __bf16* __restrict__ d1, int n1,
                        const float* __restrict__ s2, __bf16* __restrict__ d2, int n2,
                        const float* __restrict__ s3, __bf16* __restrict__ d3, int n3,
                        const float* __restrict__ s4, __bf16* __restrict__ d4, int n4){
  long i = ((long)blockIdx.x*256 + threadIdx.x)*4;
  const float* s; __bf16* d;
  if(i<n0){ s=s0; d=d0; }
  else { i-=n0; if(i<n1){ s=s1; d=d1; }
  else { i-=n1; if(i<n2){ s=s2; d=d2; }
  else { i-=n2; if(i<n3){ s=s3; d=d3; }
  else { i-=n3; if(i>=n4) return; s=s4; d=d4; } } } }
  float4 v=*(const float4*)(s+i);
  bf16x4 o; o[0]=(__bf16)v.x; o[1]=(__bf16)v.y; o[2]=(__bf16)v.z; o[3]=(__bf16)v.w;
  *(bf16x4*)(d+i)=o;
}

// ------- gate-others features: LN([t,s,|t-s|]) -> bf16 rows (B*3 x 3072) ----
// also writes audioB (bf16 copy of tokens[:,1,:]) from the j==0 blocks
__global__ void feat_go_k(const float* __restrict__ tokens, const int* __restrict__ mask,
                          const float* __restrict__ lnw, const float* __restrict__ lnb,
                          __bf16* __restrict__ featGo, __bf16* __restrict__ audioB){
  int row=blockIdx.x; int b=row/3; int j=row-b*3; int oj=(j==0)?0:(j+1);
  const float* to=tokens+((size_t)b*4+oj)*HH;
  const float* ta=tokens+((size_t)b*4+1)*HH;
  float mo = mask[b*4+oj]?1.f:0.f;
  int tid=threadIdx.x;
  __shared__ float sc[4];
  float ov[4], av[4], dv[4]; float s=0.f,s2=0.f;
#pragma unroll
  for(int p=0;p<4;p++){
    int h=tid+p*256;
    float o=to[h]*mo, a=ta[h], d=fabsf(o-a);
    ov[p]=o; av[p]=a; dv[p]=d;
    s+=o+a+d; s2+=o*o+a*a+d*d;
  }
  s=blockSum256(s,sc); s2=blockSum256(s2,sc);
  float mean=s/(float)D3, rstd=rsqrtf(s2/(float)D3-mean*mean+1e-5f);
  __bf16* fr = featGo + (size_t)row*D3;
#pragma unroll
  for(int p=0;p<4;p++){
    int h=tid+p*256;
    fr[h]       =(__bf16)((ov[p]-mean)*rstd*lnw[h]+lnb[h]);
    fr[1024+h]  =(__bf16)((av[p]-mean)*rstd*lnw[1024+h]+lnb[1024+h]);
    fr[2048+h]  =(__bf16)((dv[p]-mean)*rstd*lnw[2048+h]+lnb[2048+h]);
    if(j==0) audioB[(size_t)b*HH+h]=(__bf16)av[p];
  }
}

// ------- gate-audio features: LN([audio, omean, |diff|]) -> bf16 (B x 3072) -
__global__ void feat_ga_k(const float* __restrict__ tokens, const float* __restrict__ omean,
                          const float* __restrict__ lnw, const float* __restrict__ lnb,
                          __bf16* __restrict__ featGa){
  int b=blockIdx.x; int tid=threadIdx.x;
  const float* ta=tokens+((size_t)b*4+1)*HH;
  const float* so=omean+(size_t)b*HH;
  __shared__ float sc[4];
  float tv[4], sv[4], dv[4]; float s=0.f,s2=0.f;
#pragma unroll
  for(int p=0;p<4;p++){
    int h=tid+p*256;
    float a=ta[h], o=so[h], d=fabsf(a-o);
    tv[p]=a; sv[p]=o; dv[p]=d;
    s+=a+o+d; s2+=a*a+o*o+d*d;
  }
  s=blockSum256(s,sc); s2=blockSum256(s2,sc);
  float mean=s/(float)D3, rstd=rsqrtf(s2/(float)D3-mean*mean+1e-5f);
  __bf16* fr = featGa + (size_t)b*D3;
#pragma unroll
  for(int p=0;p<4;p++){
    int h=tid+p*256;
    fr[h]     =(__bf16)((tv[p]-mean)*rstd*lnw[h]+lnb[h]);
    fr[1024+h]=(__bf16)((sv[p]-mean)*rstd*lnw[1024+h]+lnb[1024+h]);
    fr[2048+h]=(__bf16)((dv[p]-mean)*rstd*lnw[2048+h]+lnb[2048+h]);
  }
}

// -------- unified bf16 MFMA NT GEMM: C = act(A @ B^T [+ bias]) --------------
// A: M x K bf16 (lda), B: N x K bf16 (ldb), C: M x N fp32 (ldc).
// 128x128 tile, BK=32, 4 waves, 16x16x32 MFMA, swizzled LDS granules.
template<int ACT>
__launch_bounds__(256, 2)
__global__ void gemm_nt_mfma(const __bf16* __restrict__ A, int lda,
                             const __bf16* __restrict__ Bm, int ldb,
                             const float* __restrict__ bias,
                             float* __restrict__ C, int ldc, int K){
  __shared__ __align__(16) __bf16 As[128*32];
  __shared__ __align__(16) __bf16 Bs[128*32];
  const int tid=threadIdx.x, l=tid&63, w=tid>>6;
  const int wr=w>>1, wc=w&1;
  const int quad=l>>4, lr16=l&15;
  const int row0=blockIdx.y*128, col0=blockIdx.x*128;
  const int srow=l>>2, sq=(l&3)^((l>>3)&3);
  f32x4 acc[4][4];
  f32x4 zerov={0.f,0.f,0.f,0.f};
#pragma unroll
  for(int i=0;i<4;i++)
#pragma unroll
    for(int j=0;j<4;j++) acc[i][j]=zerov;
  for(int k0=0;k0<K;k0+=32){
    __syncthreads();
#pragma unroll
    for(int t=0;t<2;t++){
      int ch=w+4*t;
      gl_lds16(A  + (size_t)(row0+ch*16+srow)*lda + k0 + sq*8, As + (size_t)(ch*64+l)*8);
      gl_lds16(Bm + (size_t)(col0+ch*16+srow)*ldb + k0 + sq*8, Bs + (size_t)(ch*64+l)*8);
    }
    __syncthreads();
    bf16x8 af[4], bg[4];
#pragma unroll
    for(int fi=0;fi<4;fi++){
      int R=wr*64+fi*16+lr16;
      af[fi]=*(const bf16x8*)(As + R*32 + ((quad^(R>>1))&3)*8);
    }
#pragma unroll
    for(int fj=0;fj<4;fj++){
      int N=wc*64+fj*16+lr16;
      bg[fj]=*(const bf16x8*)(Bs + N*32 + ((quad^(N>>1))&3)*8);
    }
#pragma unroll
    for(int fi=0;fi<4;fi++)
#pragma unroll
      for(int fj=0;fj<4;fj++)
        acc[fi][fj]=__builtin_amdgcn_mfma_f32_16x16x32_bf16(af[fi],bg[fj],acc[fi][fj],0,0,0);
  }
  float bv[4];
#pragma unroll
  for(int fj=0;fj<4;fj++) bv[fj] = (ACT==1)? bias[col0+wc*64+fj*16+lr16] : 0.f;
#pragma unroll
  for(int fi=0;fi<4;fi++){
#pragma unroll
    for(int reg=0;reg<4;reg++){
      int row=row0+wr*64+fi*16+quad*4+reg;
#pragma unroll
      for(int fj=0;fj<4;fj++){
        int col=col0+wc*64+fj*16+lr16;
        float v=acc[fi][fj][reg];
        if(ACT==1) v=gelu_f(v+bv[fj]);
        C[(size_t)row*ldc+col]=v;
      }
    }
  }
}

// ---------------- gate reduce: g = sigmoid(H . w2 + b2) ---------------------
__global__ void gate_reduce_k(const float* __restrict__ Hx, const float* __restrict__ w2,
                              const float* __restrict__ b2, float* __restrict__ g, int cols){
  int row=blockIdx.x;
  float s=0.f;
  for(int c=threadIdx.x;c<cols;c+=64) s += Hx[(size_t)row*cols+c]*w2[c];
  s=waveSum(s);
  if(threadIdx.x==0) g[row]=1.f/(1.f+expf(-(s+b2[0])));
}

// ------- others_new (into mixedB slots 0,2,3) + others_mean (f32 + bf16) ----
__global__ void others_k(const float* __restrict__ tokens, const int* __restrict__ mask,
                         const float* __restrict__ g, const float* __restrict__ a2o,
                         const float* __restrict__ lnw, const float* __restrict__ lnb,
                         __bf16* __restrict__ mixedB, float* __restrict__ omean,
                         __bf16* __restrict__ omeanB){
  int b=blockIdx.x, tid=threadIdx.x;
  __shared__ float sc[4];
  float ma = mask[b*4+1]?1.f:0.f;
  float a2[4];
#pragma unroll
  for(int p=0;p<4;p++) a2[p]=a2o[(size_t)b*HH+tid+p*256];
  float sum[4]={0,0,0,0}; float cnt=0.f;
  for(int j=0;j<3;j++){
    int oj=(j==0)?0:(j+1);
    float mo=mask[b*4+oj]?1.f:0.f; cnt+=mo;
    float gv=g[b*3+j];
    float t[4], ov[4]; float s=0.f,s2=0.f;
#pragma unroll
    for(int p=0;p<4;p++){
      int h=tid+p*256;
      float o=tokens[((size_t)b*4+oj)*HH+h]*mo;
      ov[p]=o; t[p]=o+gv*a2[p];
      s+=t[p]; s2+=t[p]*t[p];
    }
    s=blockSum256(s,sc); s2=blockSum256(s2,sc);
    float mean=s/1024.f, rstd=rsqrtf(s2/1024.f-mean*mean+1e-5f);
    float pv=mo*ma;
#pragma unroll
    for(int p=0;p<4;p++){
      int h=tid+p*256;
      float upd=(t[p]-mean)*rstd*lnw[h]+lnb[h];
      float on=((pv>0.5f)?upd:ov[p])*mo;
      mixedB[(size_t)b*4096 + (size_t)oj*HH + h]=(__bf16)on;
      sum[p]+=on*mo;
    }
  }
  float denom=fmaxf(cnt,1.f);
#pragma unroll
  for(int p=0;p<4;p++){
    float v=sum[p]/denom;
    omean[(size_t)b*HH+tid+p*256]=v;
    omeanB[(size_t)b*HH+tid+p*256]=(__bf16)v;
  }
}

// ---------------- mixed_audio (into mixedB slot 1, bf16) --------------------
__global__ void audio_k(const float* __restrict__ tokens, const int* __restrict__ mask,
                        const float* __restrict__ g_a, const float* __restrict__ o2a,
                        const float* __restrict__ lnw, const float* __restrict__ lnb,
                        __bf16* __restrict__ mixedB){
  int b=blockIdx.x, tid=threadIdx.x;
  __shared__ float sc[4];
  int ma_i=mask[b*4+1];
  int any = mask[b*4+0]|mask[b*4+2]|mask[b*4+3];
  bool aum = (ma_i!=0) && (any!=0);
  float ma = ma_i?1.f:0.f;
  float gv=g_a[b];
  const float* ta = tokens + ((size_t)b*4+1)*HH;
  float av[4], t[4]; float s=0.f,s2=0.f;
#pragma unroll
  for(int p=0;p<4;p++){
    int h=tid+p*256;
    av[p]=ta[h];
    t[p]=av[p]+gv*o2a[(size_t)b*HH+h];
    s+=t[p]; s2+=t[p]*t[p];
  }
  s=blockSum256(s,sc); s2=blockSum256(s2,sc);
  float mean=s/1024.f, rstd=rsqrtf(s2/1024.f-mean*mean+1e-5f);
#pragma unroll
  for(int p=0;p<4;p++){
    int h=tid+p*256;
    float u=(t[p]-mean)*rstd*lnw[h]+lnb[h];
    float outv = aum ? u : av[p]*ma;
    mixedB[(size_t)b*4096 + HH + h]=(__bf16)(outv*ma);
  }
}

// ------- factors [mr][1025][1024] fp32 -> factT [mr][h][d] bf16 (d=1..1024) -
__global__ void transpose_factors_k(const float* __restrict__ factors,
                                    __bf16* __restrict__ factT){
  __shared__ float T[64][65];
  int mr = blockIdx.z;
  int d0 = blockIdx.y*64, h0 = blockIdx.x*64;
  int t = threadIdx.x;
  int rr = t>>4, cc = (t&15)*4;
  const float* src = factors + ((size_t)mr*1025 + 1 + d0)*1024 + h0;
#pragma unroll
  for(int q=0;q<4;q++){
    float4 v = *(const float4*)(src + (size_t)(q*16+rr)*1024 + cc);
    T[q*16+rr][cc]=v.x; T[q*16+rr][cc+1]=v.y; T[q*16+rr][cc+2]=v.z; T[q*16+rr][cc+3]=v.w;
  }
  __syncthreads();
  __bf16* dst = factT + ((size_t)mr*1024 + h0)*1024 + d0;
#pragma unroll
  for(int q=0;q<4;q++){
    int hr = q*16 + rr;
    bf16x4 o;
    o[0]=(__bf16)T[cc][hr];   o[1]=(__bf16)T[cc+1][hr];
    o[2]=(__bf16)T[cc+2][hr]; o[3]=(__bf16)T[cc+3][hr];
    *(bf16x4*)(dst + (size_t)hr*1024 + cc) = o;
  }
}

// -------- LMF MFMA GEMM: P[b,r,h] = prod_m (mask[b,m] ? z_m[b,r,h] : 1) -----
// 3-buffer depth-2 prefetch pipeline, counted vmcnt(4), 1 raw barrier/K-step.
// acc initialized to F0 (d=0 factor row) so no epilogue add is needed.
// XCD-aware block swizzle: 2560 blocks, 8 XCDs, 320/XCD contiguous chunks.
__launch_bounds__(256, 2)
__global__ void gemm_lmf_mfma(const __bf16* __restrict__ mixedB,
                              const __bf16* __restrict__ factT,
                              const float* __restrict__ factors,
                              const int* __restrict__ mask,
                              float* __restrict__ P){
  __shared__ __align__(16) __bf16 As[3*4096];   // 3 bufs x 128x32
  __shared__ __align__(16) __bf16 Bs[3*4096];
  __shared__ float Mskf[4][128];
  __shared__ float F0s[4][128];
  const int tid = threadIdx.x;
  const int l = tid & 63, w = tid >> 6;
  const int wr = w >> 1, wc = w & 1;
  const int quad = l >> 4, lr16 = l & 15;

  // T1 XCD swizzle: HW round-robins consecutive flat ids across 8 XCDs.
  // Map so each XCD gets a contiguous chunk of original tiles (A-panel reuse
  // within one L2 instead of 8-way replication). 2560 % 8 == 0 -> bijective.
  const int flat = blockIdx.x + 8*(blockIdx.y + 32*blockIdx.z);
  const int nid  = (flat & 7)*320 + (flat >> 3);
  const int bx   = nid & 7;
  const int rest = nid >> 3;
  const int by   = rest & 31;
  const int r    = rest >> 5;
  const int row0 = by * 128, col0 = bx * 128;

  const int srow = l >> 2;
  const int sq   = (l & 3) ^ ((l >> 3) & 3);

  // ---- prologue: masks + F0 row into LDS ----
  for(int i = tid; i < 512; i += 256){
    int mm = i >> 7, rl = i & 127;
    Mskf[mm][rl] = mask[(row0 + rl)*4 + mm] ? 1.f : 0.f;
    F0s[mm][rl]  = factors[(size_t)(mm*RR + r)*1025*1024 + col0 + rl];
  }

  // per-thread global source bases (m=0, k0=0) and LDS dests
  const __bf16* pa0 = mixedB + (size_t)(row0 + w*16     + srow)*4096 + sq*8;
  const __bf16* pa1 = mixedB + (size_t)(row0 + (w+4)*16 + srow)*4096 + sq*8;
  const __bf16* pb0 = factT + ((size_t)r*1024 + col0 + w*16     + srow)*1024 + sq*8;
  const __bf16* pb1 = factT + ((size_t)r*1024 + col0 + (w+4)*16 + srow)*1024 + sq*8;
  __bf16* da0 = As + ((size_t)w*64     + l)*8;
  __bf16* da1 = As + ((size_t)(w+4)*64 + l)*8;
  __bf16* db0 = Bs + ((size_t)w*64     + l)*8;
  __bf16* db1 = Bs + ((size_t)(w+4)*64 + l)*8;

  auto stage = [&](int s, int bi){
    int mm = s >> 5; int k0 = (s & 31)*32;
    size_t ao = (size_t)mm*1024 + k0;               // mixedB: +m*1024 cols
    size_t bo = (size_t)mm*(RR*1048576) + k0;       // factT: +m*RR*1024*1024
    gl_lds16(pa0 + ao, da0 + bi*4096);
    gl_lds16(pa1 + ao, da1 + bi*4096);
    gl_lds16(pb0 + bo, db0 + bi*4096);
    gl_lds16(pb1 + bo, db1 + bi*4096);
  };

  f32x4 prod[4][4];
  f32x4 onev = {1.f,1.f,1.f,1.f};
#pragma unroll
  for(int i=0;i<4;i++)
#pragma unroll
    for(int j=0;j<4;j++) prod[i][j] = onev;

  // stage steps 0 and 1; wait step 0 (8 outstanding -> allow newest 4)
  stage(0, 0);
  stage(1, 1);
  asm volatile("s_waitcnt vmcnt(4)" ::: "memory");
  asm volatile("s_waitcnt lgkmcnt(0)" ::: "memory");   // Mskf/F0s visible
  __builtin_amdgcn_s_barrier();

  f32x4 acc[4][4];
  int cur = 0;
  for(int step = 0; step < 128; ++step){
    // ---- ds_read current buffer ----
    const __bf16* Ab = As + cur*4096;
    const __bf16* Bb = Bs + cur*4096;
    bf16x8 af[4], bg[4];
#pragma unroll
    for(int fi=0;fi<4;fi++){
      int R = wr*64 + fi*16 + lr16;
      af[fi] = *(const bf16x8*)(Ab + R*32 + ((quad ^ (R>>1)) & 3)*8);
    }
#pragma unroll
    for(int fj=0;fj<4;fj++){
      int N = wc*64 + fj*16 + lr16;
      bg[fj] = *(const bf16x8*)(Bb + N*32 + ((quad ^ (N>>1)) & 3)*8);
    }
    // ---- issue prefetch for step+2 into the third buffer ----
    if(step + 2 < 128){
      int bi = cur + 2; if(bi >= 3) bi -= 3;
      stage(step + 2, bi);
    }
    // ---- per-m accumulator init: acc = F0 (broadcast per column) ----
    if((step & 31) == 0){
      int mm = step >> 5;
#pragma unroll
      for(int fj=0;fj<4;fj++){
        float f0 = F0s[mm][wc*64 + fj*16 + lr16];
        f32x4 iv = {f0,f0,f0,f0};
#pragma unroll
        for(int fi=0;fi<4;fi++) acc[fi][fj] = iv;
      }
    }
    // ---- MFMA cluster ----
    __builtin_amdgcn_s_setprio(1);
#pragma unroll
    for(int fi=0;fi<4;fi++)
#pragma unroll
      for(int fj=0;fj<4;fj++)
        acc[fi][fj] = __builtin_amdgcn_mfma_f32_16x16x32_bf16(af[fi], bg[fj], acc[fi][fj], 0,0,0);
    __builtin_amdgcn_s_setprio(0);
    // ---- per-m epilogue: fold into masked product ----
    if((step & 31) == 31){
      int mm = step >> 5;
#pragma unroll
      for(int fi=0;fi<4;fi++)
#pragma unroll
        for(int reg=0;reg<4;reg++){
          float mk = Mskf[mm][wr*64 + fi*16 + quad*4 + reg];
#pragma unroll
          for(int fj=0;fj<4;fj++)
            prod[fi][fj][reg] *= (mk != 0.f) ? acc[fi][fj][reg] : 1.f;
        }
    }
    // ---- drain ds reads; counted vmcnt keeps 4 newest loads in flight ----
    asm volatile("s_waitcnt lgkmcnt(0)" ::: "memory");
    if(step < 126) asm volatile("s_waitcnt vmcnt(4)" ::: "memory");
    else           asm volatile("s_waitcnt vmcnt(0)" ::: "memory");
    __builtin_amdgcn_s_barrier();
    cur = (cur + 1 == 3) ? 0 : cur + 1;
  }

#pragma unroll
  for(int fi=0;fi<4;fi++){
#pragma unroll
    for(int reg=0;reg<4;reg++){
      int row = row0 + wr*64 + fi*16 + quad*4 + reg;
#pragma unroll
      for(int fj=0;fj<4;fj++){
        int col = col0 + wc*64 + fj*16 + lr16;
        P[((size_t)row*RR + r)*HH + col] = prod[fi][fj][reg];
      }
    }
  }
}

// -------- fused[b,h] = sum_r rank_w[r]*P[b,r,h] + lmf_bias[h] ---------------
__global__ void fuse_k(const float* __restrict__ P, const float* __restrict__ rank_w,
                       const float* __restrict__ lmf_bias, float* __restrict__ fused){
  size_t i=(size_t)blockIdx.x*256+threadIdx.x;
  int b=(int)(i>>10), h=(int)(i&1023);
  float s=lmf_bias[h];
#pragma unroll
  for(int r=0;r<RR;r++) s += rank_w[r]*P[((size_t)b*RR+r)*HH+h];
  fused[i]=s;
}

// ---------------- row LayerNorm over H=1024 (fp32 out) ----------------------
__global__ void ln_row_k(const float* __restrict__ X, const float* __restrict__ w,
                         const float* __restrict__ bb, float* __restrict__ Y){
  int b=blockIdx.x, tid=threadIdx.x;
  __shared__ float sc[4];
  const float* x=X+(size_t)b*HH;
  float t[4]; float s=0.f,s2=0.f;
#pragma unroll
  for(int p=0;p<4;p++){ t[p]=x[tid+p*256]; s+=t[p]; s2+=t[p]*t[p]; }
  s=blockSum256(s,sc); s2=blockSum256(s2,sc);
  float mean=s/1024.f, rstd=rsqrtf(s2/1024.f-mean*mean+1e-5f);
#pragma unroll
  for(int p=0;p<4;p++){
    int h=tid+p*256;
    Y[(size_t)b*HH+h]=(t[p]-mean)*rstd*w[h]+bb[h];
  }
}
// ---------------- row LayerNorm over H=1024 (bf16 out) ----------------------
__global__ void ln_row_bf16_k(const float* __restrict__ X, const float* __restrict__ w,
                              const float* __restrict__ bb, __bf16* __restrict__ Y){
  int b=blockIdx.x, tid=threadIdx.x;
  __shared__ float sc[4];
  const float* x=X+(size_t)b*HH;
  float t[4]; float s=0.f,s2=0.f;
#pragma unroll
  for(int p=0;p<4;p++){ t[p]=x[tid+p*256]; s+=t[p]; s2+=t[p]*t[p]; }
  s=blockSum256(s,sc); s2=blockSum256(s2,sc);
  float mean=s/1024.f, rstd=rsqrtf(s2/1024.f-mean*mean+1e-5f);
#pragma unroll
  for(int p=0;p<4;p++){
    int h=tid+p*256;
    Y[(size_t)b*HH+h]=(__bf16)((t[p]-mean)*rstd*w[h]+bb[h]);
  }
}

// ---------------- launch ----------------------------------------------------
extern "C" void kernel_launch(void* const* d_in, const int* in_sizes, int n_in,
                              void* d_out, int out_size, void* d_ws, size_t ws_size,
                              hipStream_t stream) {
  const float* tokens   =(const float*)d_in[0];
  const int*   mask     =(const int*)  d_in[1];
  const float* ln_go_w  =(const float*)d_in[2];
  const float* ln_go_b  =(const float*)d_in[3];
  const float* go_w1    =(const float*)d_in[4];
  const float* go_b1    =(const float*)d_in[5];
  const float* go_w2    =(const float*)d_in[6];
  const float* go_b2    =(const float*)d_in[7];
  const float* ln_ga_w  =(const float*)d_in[8];
  const float* ln_ga_b  =(const float*)d_in[9];
  const float* ga_w1    =(const float*)d_in[10];
  const float* ga_b1    =(const float*)d_in[11];
  const float* ga_w2    =(const float*)d_in[12];
  const float* ga_b2    =(const float*)d_in[13];
  const float* a2o_w    =(const float*)d_in[14];
  const float* o2a_w    =(const float*)d_in[15];
  const float* ln_o_w   =(const float*)d_in[16];
  const float* ln_o_b   =(const float*)d_in[17];
  const float* ln_a_w   =(const float*)d_in[18];
  const float* ln_a_b   =(const float*)d_in[19];
  const float* factors  =(const float*)d_in[20];
  const float* rank_w   =(const float*)d_in[21];
  const float* lmf_bias =(const float*)d_in[22];
  const float* out_ln1_w=(const float*)d_in[23];
  const float* out_ln1_b=(const float*)d_in[24];
  const float* out_w    =(const float*)d_in[25];
  const float* out_b    =(const float*)d_in[26];
  const float* out_ln2_w=(const float*)d_in[27];
  const float* out_ln2_b=(const float*)d_in[28];
  float* out=(float*)d_out;

  char* wsp=(char*)d_ws; size_t off=0;
  auto alloc=[&](size_t bytes)->void*{
    void* p=wsp+off; off=(off+bytes+255)&~(size_t)255; return p;
  };
  float*  P       =(float*) alloc((size_t)BB*RR*HH*4);      // 168 MB
  __bf16* factT   =(__bf16*)alloc((size_t)4*RR*HH*HH*2);    // 84 MB
  float*  H1      =(float*) alloc((size_t)BB*3*MIDD*4);
  float*  g_go    =(float*) alloc((size_t)BB*3*4);
  float*  a2o     =(float*) alloc((size_t)BB*HH*4);
  __bf16* mixedB  =(__bf16*)alloc((size_t)BB*4*HH*2);
  float*  omean   =(float*) alloc((size_t)BB*HH*4);
  __bf16* omeanB  =(__bf16*)alloc((size_t)BB*HH*2);
  __bf16* audioB  =(__bf16*)alloc((size_t)BB*HH*2);
  float*  H2      =(float*) alloc((size_t)BB*MIDD*4);
  float*  g_a     =(float*) alloc((size_t)BB*4);
  float*  o2a     =(float*) alloc((size_t)BB*HH*4);
  float*  fused   =(float*) alloc((size_t)BB*HH*4);
  __bf16* hbufB   =(__bf16*)alloc((size_t)BB*HH*2);
  __bf16* go_w1B  =(__bf16*)alloc((size_t)MIDD*D3*2);
  __bf16* ga_w1B  =(__bf16*)alloc((size_t)MIDD*D3*2);
  __bf16* a2o_wB  =(__bf16*)alloc((size_t)HH*HH*2);
  __bf16* o2a_wB  =(__bf16*)alloc((size_t)HH*HH*2);
  __bf16* out_wB  =(__bf16*)alloc((size_t)HH*HH*2);
  // feat buffers alias P (dead before lmf writes P): featGo 75.5MB + featGa 25.2MB < 168MB
  __bf16* featGo  =(__bf16*)P;
  __bf16* featGa  =(__bf16*)((char*)P + (size_t)BB*3*D3*2);

  // 0) weight converts + factor transpose (independent)
  {
    int n0=MIDD*D3, n1=MIDD*D3, n2=HH*HH, n3=HH*HH, n4=HH*HH;
    int total4=(n0+n1+n2+n3+n4)/4;
    convw_k<<<(total4+255)/256,256,0,stream>>>(go_w1,go_w1B,n0, ga_w1,ga_w1B,n1,
                                               a2o_w,a2o_wB,n2, o2a_w,o2a_wB,n3,
                                               out_w,out_wB,n4);
  }
  transpose_factors_k<<<dim3(16,16,40),256,0,stream>>>(factors,factT);
  // 1) gate-others features (bf16, LN applied) + audioB
  feat_go_k<<<BB*3,256,0,stream>>>(tokens,mask,ln_go_w,ln_go_b,featGo,audioB);
  // 2) a2o = audio @ a2o_w^T   (bf16 MFMA)
  gemm_nt_mfma<0><<<dim3(8,32),256,0,stream>>>(audioB,HH,a2o_wB,HH,nullptr,a2o,HH,HH);
  // 3) H1 = gelu(featGo @ go_w1^T + go_b1)
  gemm_nt_mfma<1><<<dim3(4,96),256,0,stream>>>(featGo,D3,go_w1B,D3,go_b1,H1,MIDD,D3);
  // 4) g_go
  gate_reduce_k<<<BB*3,64,0,stream>>>(H1,go_w2,go_b2,g_go,MIDD);
  // 5) others_new -> mixedB {0,2,3}; others_mean (f32+bf16)
  others_k<<<BB,256,0,stream>>>(tokens,mask,g_go,a2o,ln_o_w,ln_o_b,mixedB,omean,omeanB);
  // 6) gate-audio features
  feat_ga_k<<<BB,256,0,stream>>>(tokens,omean,ln_ga_w,ln_ga_b,featGa);
  // 7) H2 = gelu(featGa @ ga_w1^T + ga_b1)
  gemm_nt_mfma<1><<<dim3(4,32),256,0,stream>>>(featGa,D3,ga_w1B,D3,ga_b1,H2,MIDD,D3);
  // 8) g_a
  gate_reduce_k<<<BB,64,0,stream>>>(H2,ga_w2,ga_b2,g_a,MIDD);
  // 9) o2a = others_mean @ o2a_w^T
  gemm_nt_mfma<0><<<dim3(8,32),256,0,stream>>>(omeanB,HH,o2a_wB,HH,nullptr,o2a,HH,HH);
  // 10) mixed_audio -> mixedB slot 1
  audio_k<<<BB,256,0,stream>>>(tokens,mask,g_a,o2a,ln_a_w,ln_a_b,mixedB);
  // 11) LMF rank product (MFMA, all m fused, pipelined, XCD-swizzled)
  gemm_lmf_mfma<<<dim3(HH/128,BB/128,RR),256,0,stream>>>(mixedB,factT,factors,mask,P);
  // 12) fused = sum_r rank_w[r]*P + lmf_bias
  fuse_k<<<(BB*HH)/256,256,0,stream>>>(P,rank_w,lmf_bias,fused);
  // 13) hbufB = LN(fused) as bf16
  ln_row_bf16_k<<<BB,256,0,stream>>>(fused,out_ln1_w,out_ln1_b,hbufB);
  // 14) fused = gelu(hbufB @ out_w^T + out_b)
  gemm_nt_mfma<1><<<dim3(8,32),256,0,stream>>>(hbufB,HH,out_wB,HH,out_b,fused,HH,HH);
  // 15) out = LN(fused)
  ln_row_k<<<BB,256,0,stream>>>(fused,out_ln2_w,out_ln2_b,out);
}

// Round 3
// 1031.422 us; speedup vs baseline: 1.3726x; 1.0921x over previous
//
#include <hip/hip_runtime.h>
#include <math.h>

#define BB 4096
#define HH 1024
#define RR 10
#define MIDD 512
#define D3 3072

typedef __bf16 bf16x8 __attribute__((ext_vector_type(8)));
typedef __bf16 bf16x4 __attribute__((ext_vector_type(4)));
typedef float f32x4 __attribute__((ext_vector_type(4)));

// ---------------- reduction helpers ----------------
__device__ __forceinline__ float waveSum(float v){
#pragma unroll
  for(int o=32;o>0;o>>=1) v += __shfl_down(v,o,64);
  return v;
}
__device__ __forceinline__ float blockSum256(float v, float* sc){
  v = waveSum(v);
  __syncthreads();
  if((threadIdx.x & 63)==0) sc[threadIdx.x>>6] = v;
  __syncthreads();
  return sc[0]+sc[1]+sc[2]+sc[3];
}
__device__ __forceinline__ float gelu_f(float x){
  return 0.5f*x*(1.0f+erff(x*0.70710678118654752f));
}
__device__ __forceinline__ void gl_lds16(const void* g, void* lds){
  __builtin_amdgcn_global_load_lds((const __attribute__((address_space(1))) unsigned int*)g,
                                   (__attribute__((address_space(3))) unsigned int*)lds,
                                   16, 0, 0);
}

// ---------- weight convert: 5 fp32 matrices -> bf16, one launch -------------
__global__ void convw_k(const float* __restrict__ s0, __bf16* __restrict__ d0, int n0,
                        const float* __restrict__ s1, __bf16* __restrict__ d1, int n1,
                        const float* __restrict__ s2, __bf16* __restrict__ d2, int n2,
                        const float* __restrict__ s3, __bf16* __restrict__ d3, int n3,
                        const float* __restrict__ s4, __bf16* __restrict__ d4, int n4){
  long i = ((long)blockIdx.x*256 + threadIdx.x)*4;
  const float* s; __bf16* d;
  if(i<n0){ s=s0; d=d0; }
  else { i-=n0; if(i<n1){ s=s1; d=d1; }
  else { i-=n1; if(i<n2){ s=s2; d=d2; }
  else { i-=n2; if(i<n3){ s=s3; d=d3; }
  else { i-=n3; if(i>=n4) return; s=s4; d=d4; } } } }
  float4 v=*(const float4*)(s+i);
  bf16x4 o; o[0]=(__bf16)v.x; o[1]=(__bf16)v.y; o[2]=(__bf16)v.z; o[3]=(__bf16)v.w;
  *(bf16x4*)(d+i)=o;
}

// ------- gate-others features: LN([t,s,|t-s|]) -> bf16 rows (B*3 x 3072) ----
// also writes audioB (bf16 copy of tokens[:,1,:]) from the j==0 blocks
__global__ void feat_go_k(const float* __restrict__ tokens, const int* __restrict__ mask,
                          const float* __restrict__ lnw, const float* __restrict__ lnb,
                          __bf16* __restrict__ featGo, __bf16* __restrict__ audioB){
  int row=blockIdx.x; int b=row/3; int j=row-b*3; int oj=(j==0)?0:(j+1);
  const float* to=tokens+((size_t)b*4+oj)*HH;
  const float* ta=tokens+((size_t)b*4+1)*HH;
  float mo = mask[b*4+oj]?1.f:0.f;
  int tid=threadIdx.x;
  __shared__ float sc[4];
  float ov[4], av[4], dv[4]; float s=0.f,s2=0.f;
#pragma unroll
  for(int p=0;p<4;p++){
    int h=tid+p*256;
    float o=to[h]*mo, a=ta[h], d=fabsf(o-a);
    ov[p]=o; av[p]=a; dv[p]=d;
    s+=o+a+d; s2+=o*o+a*a+d*d;
  }
  s=blockSum256(s,sc); s2=blockSum256(s2,sc);
  float mean=s/(float)D3, rstd=rsqrtf(s2/(float)D3-mean*mean+1e-5f);
  __bf16* fr = featGo + (size_t)row*D3;
#pragma unroll
  for(int p=0;p<4;p++){
    int h=tid+p*256;
    fr[h]       =(__bf16)((ov[p]-mean)*rstd*lnw[h]+lnb[h]);
    fr[1024+h]  =(__bf16)((av[p]-mean)*rstd*lnw[1024+h]+lnb[1024+h]);
    fr[2048+h]  =(__bf16)((dv[p]-mean)*rstd*lnw[2048+h]+lnb[2048+h]);
    if(j==0) audioB[(size_t)b*HH+h]=(__bf16)av[p];
  }
}

// ------- gate-audio features: LN([audio, omean, |diff|]) -> bf16 (B x 3072) -
__global__ void feat_ga_k(const float* __restrict__ tokens, const float* __restrict__ omean,
                          const float* __restrict__ lnw, const float* __restrict__ lnb,
                          __bf16* __restrict__ featGa){
  int b=blockIdx.x; int tid=threadIdx.x;
  const float* ta=tokens+((size_t)b*4+1)*HH;
  const float* so=omean+(size_t)b*HH;
  __shared__ float sc[4];
  float tv[4], sv[4], dv[4]; float s=0.f,s2=0.f;
#pragma unroll
  for(int p=0;p<4;p++){
    int h=tid+p*256;
    float a=ta[h], o=so[h], d=fabsf(a-o);
    tv[p]=a; sv[p]=o; dv[p]=d;
    s+=a+o+d; s2+=a*a+o*o+d*d;
  }
  s=blockSum256(s,sc); s2=blockSum256(s2,sc);
  float mean=s/(float)D3, rstd=rsqrtf(s2/(float)D3-mean*mean+1e-5f);
  __bf16* fr = featGa + (size_t)b*D3;
#pragma unroll
  for(int p=0;p<4;p++){
    int h=tid+p*256;
    fr[h]     =(__bf16)((tv[p]-mean)*rstd*lnw[h]+lnb[h]);
    fr[1024+h]=(__bf16)((sv[p]-mean)*rstd*lnw[1024+h]+lnb[1024+h]);
    fr[2048+h]=(__bf16)((dv[p]-mean)*rstd*lnw[2048+h]+lnb[2048+h]);
  }
}

// -------- unified bf16 MFMA NT GEMM: C = act(A @ B^T [+ bias]) --------------
// A: M x K bf16 (lda), B: N x K bf16 (ldb), C: M x N fp32 (ldc).
// 64x128 tile, BK=32, 4 waves (2x2, 32x64 each), 16x16x32 MFMA.
// 3-buffer depth-2 counted-vmcnt(3) pipeline + XCD swizzle, 4 blocks/CU.
template<int ACT>
__launch_bounds__(256, 4)
__global__ void gemm_nt_mfma(const __bf16* __restrict__ A, int lda,
                             const __bf16* __restrict__ Bm, int ldb,
                             const float* __restrict__ bias,
                             float* __restrict__ C, int ldc, int K){
  __shared__ __align__(16) __bf16 As[3*2048];   // 3 bufs x 64x32
  __shared__ __align__(16) __bf16 Bs[3*4096];   // 3 bufs x 128x32
  const int tid=threadIdx.x, l=tid&63, w=tid>>6;
  const int wr=w>>1, wc=w&1;
  const int quad=l>>4, lr16=l&15;

  // XCD swizzle (grid total always %8==0 here)
  const int nbx = gridDim.x;
  const int flat = blockIdx.x + nbx*blockIdx.y;
  const int chunk = (nbx*gridDim.y)>>3;
  const int nid = (flat&7)*chunk + (flat>>3);
  const int bx = nid % nbx, by = nid / nbx;
  const int row0=by*64, col0=bx*128;

  const int srow=l>>2, sq=(l&3)^((l>>3)&3);
  const int nsteps = K>>5;

  const __bf16* pa  = A  + (size_t)(row0 + w*16       + srow)*lda + sq*8;
  const __bf16* pb0 = Bm + (size_t)(col0 + w*16       + srow)*ldb + sq*8;
  const __bf16* pb1 = Bm + (size_t)(col0 + (w+4)*16   + srow)*ldb + sq*8;
  __bf16* da  = As + ((size_t)w*64     + l)*8;
  __bf16* db0 = Bs + ((size_t)w*64     + l)*8;
  __bf16* db1 = Bs + ((size_t)(w+4)*64 + l)*8;

  auto stage=[&](int s,int bi){
    int k0 = s*32;
    gl_lds16(pa  + k0, da  + bi*2048);
    gl_lds16(pb0 + k0, db0 + bi*4096);
    gl_lds16(pb1 + k0, db1 + bi*4096);
  };

  f32x4 acc[2][4];
  f32x4 zerov={0.f,0.f,0.f,0.f};
#pragma unroll
  for(int i=0;i<2;i++)
#pragma unroll
    for(int j=0;j<4;j++) acc[i][j]=zerov;

  stage(0,0);
  stage(1,1);
  asm volatile("s_waitcnt vmcnt(3)" ::: "memory");
  __builtin_amdgcn_s_barrier();

  int cur=0;
  for(int step=0; step<nsteps; ++step){
    const __bf16* Ab = As + cur*2048;
    const __bf16* Bb = Bs + cur*4096;
    bf16x8 af[2], bg[4];
#pragma unroll
    for(int fi=0;fi<2;fi++){
      int R = wr*32 + fi*16 + lr16;
      af[fi]=*(const bf16x8*)(Ab + R*32 + ((quad^(R>>1))&3)*8);
    }
#pragma unroll
    for(int fj=0;fj<4;fj++){
      int N = wc*64 + fj*16 + lr16;
      bg[fj]=*(const bf16x8*)(Bb + N*32 + ((quad^(N>>1))&3)*8);
    }
    if(step+2<nsteps){
      int bi = cur + 2; if(bi>=3) bi-=3;
      stage(step+2, bi);
    }
    __builtin_amdgcn_s_setprio(1);
#pragma unroll
    for(int fi=0;fi<2;fi++)
#pragma unroll
      for(int fj=0;fj<4;fj++)
        acc[fi][fj]=__builtin_amdgcn_mfma_f32_16x16x32_bf16(af[fi],bg[fj],acc[fi][fj],0,0,0);
    __builtin_amdgcn_s_setprio(0);
    asm volatile("s_waitcnt lgkmcnt(0)" ::: "memory");
    if(step < nsteps-2) asm volatile("s_waitcnt vmcnt(3)" ::: "memory");
    else                asm volatile("s_waitcnt vmcnt(0)" ::: "memory");
    __builtin_amdgcn_s_barrier();
    cur = (cur+1==3)?0:cur+1;
  }

  float bv[4];
#pragma unroll
  for(int fj=0;fj<4;fj++) bv[fj] = (ACT==1)? bias[col0+wc*64+fj*16+lr16] : 0.f;
#pragma unroll
  for(int fi=0;fi<2;fi++){
#pragma unroll
    for(int reg=0;reg<4;reg++){
      int row=row0+wr*32+fi*16+quad*4+reg;
#pragma unroll
      for(int fj=0;fj<4;fj++){
        int col=col0+wc*64+fj*16+lr16;
        float v=acc[fi][fj][reg];
        if(ACT==1) v=gelu_f(v+bv[fj]);
        C[(size_t)row*ldc+col]=v;
      }
    }
  }
}

// ---------------- gate reduce: g = sigmoid(H . w2 + b2) ---------------------
__global__ void gate_reduce_k(const float* __restrict__ Hx, const float* __restrict__ w2,
                              const float* __restrict__ b2, float* __restrict__ g, int cols){
  int row=blockIdx.x;
  float s=0.f;
  for(int c=threadIdx.x;c<cols;c+=64) s += Hx[(size_t)row*cols+c]*w2[c];
  s=waveSum(s);
  if(threadIdx.x==0) g[row]=1.f/(1.f+expf(-(s+b2[0])));
}

// ------- others_new (into mixedB slots 0,2,3) + others_mean (f32 + bf16) ----
__global__ void others_k(const float* __restrict__ tokens, const int* __restrict__ mask,
                         const float* __restrict__ g, const float* __restrict__ a2o,
                         const float* __restrict__ lnw, const float* __restrict__ lnb,
                         __bf16* __restrict__ mixedB, float* __restrict__ omean,
                         __bf16* __restrict__ omeanB){
  int b=blockIdx.x, tid=threadIdx.x;
  __shared__ float sc[4];
  float ma = mask[b*4+1]?1.f:0.f;
  float a2[4];
#pragma unroll
  for(int p=0;p<4;p++) a2[p]=a2o[(size_t)b*HH+tid+p*256];
  float sum[4]={0,0,0,0}; float cnt=0.f;
  for(int j=0;j<3;j++){
    int oj=(j==0)?0:(j+1);
    float mo=mask[b*4+oj]?1.f:0.f; cnt+=mo;
    float gv=g[b*3+j];
    float t[4], ov[4]; float s=0.f,s2=0.f;
#pragma unroll
    for(int p=0;p<4;p++){
      int h=tid+p*256;
      float o=tokens[((size_t)b*4+oj)*HH+h]*mo;
      ov[p]=o; t[p]=o+gv*a2[p];
      s+=t[p]; s2+=t[p]*t[p];
    }
    s=blockSum256(s,sc); s2=blockSum256(s2,sc);
    float mean=s/1024.f, rstd=rsqrtf(s2/1024.f-mean*mean+1e-5f);
    float pv=mo*ma;
#pragma unroll
    for(int p=0;p<4;p++){
      int h=tid+p*256;
      float upd=(t[p]-mean)*rstd*lnw[h]+lnb[h];
      float on=((pv>0.5f)?upd:ov[p])*mo;
      mixedB[(size_t)b*4096 + (size_t)oj*HH + h]=(__bf16)on;
      sum[p]+=on*mo;
    }
  }
  float denom=fmaxf(cnt,1.f);
#pragma unroll
  for(int p=0;p<4;p++){
    float v=sum[p]/denom;
    omean[(size_t)b*HH+tid+p*256]=v;
    omeanB[(size_t)b*HH+tid+p*256]=(__bf16)v;
  }
}

// ---------------- mixed_audio (into mixedB slot 1, bf16) --------------------
__global__ void audio_k(const float* __restrict__ tokens, const int* __restrict__ mask,
                        const float* __restrict__ g_a, const float* __restrict__ o2a,
                        const float* __restrict__ lnw, const float* __restrict__ lnb,
                        __bf16* __restrict__ mixedB){
  int b=blockIdx.x, tid=threadIdx.x;
  __shared__ float sc[4];
  int ma_i=mask[b*4+1];
  int any = mask[b*4+0]|mask[b*4+2]|mask[b*4+3];
  bool aum = (ma_i!=0) && (any!=0);
  float ma = ma_i?1.f:0.f;
  float gv=g_a[b];
  const float* ta = tokens + ((size_t)b*4+1)*HH;
  float av[4], t[4]; float s=0.f,s2=0.f;
#pragma unroll
  for(int p=0;p<4;p++){
    int h=tid+p*256;
    av[p]=ta[h];
    t[p]=av[p]+gv*o2a[(size_t)b*HH+h];
    s+=t[p]; s2+=t[p]*t[p];
  }
  s=blockSum256(s,sc); s2=blockSum256(s2,sc);
  float mean=s/1024.f, rstd=rsqrtf(s2/1024.f-mean*mean+1e-5f);
#pragma unroll
  for(int p=0;p<4;p++){
    int h=tid+p*256;
    float u=(t[p]-mean)*rstd*lnw[h]+lnb[h];
    float outv = aum ? u : av[p]*ma;
    mixedB[(size_t)b*4096 + HH + h]=(__bf16)(outv*ma);
  }
}

// ------- factors [mr][1025][1024] fp32 -> factT [mr][h][d] bf16 (d=1..1024) -
__global__ void transpose_factors_k(const float* __restrict__ factors,
                                    __bf16* __restrict__ factT){
  __shared__ float T[64][65];
  int mr = blockIdx.z;
  int d0 = blockIdx.y*64, h0 = blockIdx.x*64;
  int t = threadIdx.x;
  int rr = t>>4, cc = (t&15)*4;
  const float* src = factors + ((size_t)mr*1025 + 1 + d0)*1024 + h0;
#pragma unroll
  for(int q=0;q<4;q++){
    float4 v = *(const float4*)(src + (size_t)(q*16+rr)*1024 + cc);
    T[q*16+rr][cc]=v.x; T[q*16+rr][cc+1]=v.y; T[q*16+rr][cc+2]=v.z; T[q*16+rr][cc+3]=v.w;
  }
  __syncthreads();
  __bf16* dst = factT + ((size_t)mr*1024 + h0)*1024 + d0;
#pragma unroll
  for(int q=0;q<4;q++){
    int hr = q*16 + rr;
    bf16x4 o;
    o[0]=(__bf16)T[cc][hr];   o[1]=(__bf16)T[cc+1][hr];
    o[2]=(__bf16)T[cc+2][hr]; o[3]=(__bf16)T[cc+3][hr];
    *(bf16x4*)(dst + (size_t)hr*1024 + cc) = o;
  }
}

// -------- LMF MFMA GEMM: P[b,r,h] = prod_m (mask[b,m] ? z_m[b,r,h] : 1) -----
// 3-buffer depth-2 prefetch pipeline, counted vmcnt(4), 1 raw barrier/K-step.
// acc initialized to F0 (d=0 factor row) so no epilogue add is needed.
// XCD-aware block swizzle: 2560 blocks, 8 XCDs, 320/XCD contiguous chunks.
__launch_bounds__(256, 2)
__global__ void gemm_lmf_mfma(const __bf16* __restrict__ mixedB,
                              const __bf16* __restrict__ factT,
                              const float* __restrict__ factors,
                              const int* __restrict__ mask,
                              float* __restrict__ P){
  __shared__ __align__(16) __bf16 As[3*4096];   // 3 bufs x 128x32
  __shared__ __align__(16) __bf16 Bs[3*4096];
  __shared__ float Mskf[4][128];
  __shared__ float F0s[4][128];
  const int tid = threadIdx.x;
  const int l = tid & 63, w = tid >> 6;
  const int wr = w >> 1, wc = w & 1;
  const int quad = l >> 4, lr16 = l & 15;

  const int flat = blockIdx.x + 8*(blockIdx.y + 32*blockIdx.z);
  const int nid  = (flat & 7)*320 + (flat >> 3);
  const int bx   = nid & 7;
  const int rest = nid >> 3;
  const int by   = rest & 31;
  const int r    = rest >> 5;
  const int row0 = by * 128, col0 = bx * 128;

  const int srow = l >> 2;
  const int sq   = (l & 3) ^ ((l >> 3) & 3);

  // ---- prologue: masks + F0 row into LDS ----
  for(int i = tid; i < 512; i += 256){
    int mm = i >> 7, rl = i & 127;
    Mskf[mm][rl] = mask[(row0 + rl)*4 + mm] ? 1.f : 0.f;
    F0s[mm][rl]  = factors[(size_t)(mm*RR + r)*1025*1024 + col0 + rl];
  }

  const __bf16* pa0 = mixedB + (size_t)(row0 + w*16     + srow)*4096 + sq*8;
  const __bf16* pa1 = mixedB + (size_t)(row0 + (w+4)*16 + srow)*4096 + sq*8;
  const __bf16* pb0 = factT + ((size_t)r*1024 + col0 + w*16     + srow)*1024 + sq*8;
  const __bf16* pb1 = factT + ((size_t)r*1024 + col0 + (w+4)*16 + srow)*1024 + sq*8;
  __bf16* da0 = As + ((size_t)w*64     + l)*8;
  __bf16* da1 = As + ((size_t)(w+4)*64 + l)*8;
  __bf16* db0 = Bs + ((size_t)w*64     + l)*8;
  __bf16* db1 = Bs + ((size_t)(w+4)*64 + l)*8;

  auto stage = [&](int s, int bi){
    int mm = s >> 5; int k0 = (s & 31)*32;
    size_t ao = (size_t)mm*1024 + k0;               // mixedB: +m*1024 cols
    size_t bo = (size_t)mm*(RR*1048576) + k0;       // factT: +m*RR*1024*1024
    gl_lds16(pa0 + ao, da0 + bi*4096);
    gl_lds16(pa1 + ao, da1 + bi*4096);
    gl_lds16(pb0 + bo, db0 + bi*4096);
    gl_lds16(pb1 + bo, db1 + bi*4096);
  };

  f32x4 prod[4][4];
  f32x4 onev = {1.f,1.f,1.f,1.f};
#pragma unroll
  for(int i=0;i<4;i++)
#pragma unroll
    for(int j=0;j<4;j++) prod[i][j] = onev;

  stage(0, 0);
  stage(1, 1);
  asm volatile("s_waitcnt vmcnt(4)" ::: "memory");
  asm volatile("s_waitcnt lgkmcnt(0)" ::: "memory");   // Mskf/F0s visible
  __builtin_amdgcn_s_barrier();

  f32x4 acc[4][4];
  int cur = 0;
  for(int step = 0; step < 128; ++step){
    const __bf16* Ab = As + cur*4096;
    const __bf16* Bb = Bs + cur*4096;
    bf16x8 af[4], bg[4];
#pragma unroll
    for(int fi=0;fi<4;fi++){
      int R = wr*64 + fi*16 + lr16;
      af[fi] = *(const bf16x8*)(Ab + R*32 + ((quad ^ (R>>1)) & 3)*8);
    }
#pragma unroll
    for(int fj=0;fj<4;fj++){
      int N = wc*64 + fj*16 + lr16;
      bg[fj] = *(const bf16x8*)(Bb + N*32 + ((quad ^ (N>>1)) & 3)*8);
    }
    if(step + 2 < 128){
      int bi = cur + 2; if(bi >= 3) bi -= 3;
      stage(step + 2, bi);
    }
    if((step & 31) == 0){
      int mm = step >> 5;
#pragma unroll
      for(int fj=0;fj<4;fj++){
        float f0 = F0s[mm][wc*64 + fj*16 + lr16];
        f32x4 iv = {f0,f0,f0,f0};
#pragma unroll
        for(int fi=0;fi<4;fi++) acc[fi][fj] = iv;
      }
    }
    __builtin_amdgcn_s_setprio(1);
#pragma unroll
    for(int fi=0;fi<4;fi++)
#pragma unroll
      for(int fj=0;fj<4;fj++)
        acc[fi][fj] = __builtin_amdgcn_mfma_f32_16x16x32_bf16(af[fi], bg[fj], acc[fi][fj], 0,0,0);
    __builtin_amdgcn_s_setprio(0);
    if((step & 31) == 31){
      int mm = step >> 5;
#pragma unroll
      for(int fi=0;fi<4;fi++)
#pragma unroll
        for(int reg=0;reg<4;reg++){
          float mk = Mskf[mm][wr*64 + fi*16 + quad*4 + reg];
#pragma unroll
          for(int fj=0;fj<4;fj++)
            prod[fi][fj][reg] *= (mk != 0.f) ? acc[fi][fj][reg] : 1.f;
        }
    }
    asm volatile("s_waitcnt lgkmcnt(0)" ::: "memory");
    if(step < 126) asm volatile("s_waitcnt vmcnt(4)" ::: "memory");
    else           asm volatile("s_waitcnt vmcnt(0)" ::: "memory");
    __builtin_amdgcn_s_barrier();
    cur = (cur + 1 == 3) ? 0 : cur + 1;
  }

#pragma unroll
  for(int fi=0;fi<4;fi++){
#pragma unroll
    for(int reg=0;reg<4;reg++){
      int row = row0 + wr*64 + fi*16 + quad*4 + reg;
#pragma unroll
      for(int fj=0;fj<4;fj++){
        int col = col0 + wc*64 + fj*16 + lr16;
        P[((size_t)row*RR + r)*HH + col] = prod[fi][fj][reg];
      }
    }
  }
}

// ---- fused LN(sum_r rank_w[r]*P[b,r,:] + lmf_bias) -> bf16 (one pass) ------
__global__ void fuse_ln_k(const float* __restrict__ P, const float* __restrict__ rank_w,
                          const float* __restrict__ lmf_bias,
                          const float* __restrict__ w, const float* __restrict__ bb,
                          __bf16* __restrict__ Y){
  int b=blockIdx.x, tid=threadIdx.x;
  __shared__ float sc[4];
  float rw[RR];
#pragma unroll
  for(int r=0;r<RR;r++) rw[r]=rank_w[r];
  const float* Pb = P + (size_t)b*RR*HH;
  float t[4]; float s=0.f,s2=0.f;
#pragma unroll
  for(int p=0;p<4;p++){
    int h=tid+p*256;
    float v=lmf_bias[h];
#pragma unroll
    for(int r=0;r<RR;r++) v += rw[r]*Pb[(size_t)r*HH+h];
    t[p]=v; s+=v; s2+=v*v;
  }
  s=blockSum256(s,sc); s2=blockSum256(s2,sc);
  float mean=s/1024.f, rstd=rsqrtf(s2/1024.f-mean*mean+1e-5f);
#pragma unroll
  for(int p=0;p<4;p++){
    int h=tid+p*256;
    Y[(size_t)b*HH+h]=(__bf16)((t[p]-mean)*rstd*w[h]+bb[h]);
  }
}

// ---------------- row LayerNorm over H=1024 (fp32 out) ----------------------
__global__ void ln_row_k(const float* __restrict__ X, const float* __restrict__ w,
                         const float* __restrict__ bb, float* __restrict__ Y){
  int b=blockIdx.x, tid=threadIdx.x;
  __shared__ float sc[4];
  const float* x=X+(size_t)b*HH;
  float t[4]; float s=0.f,s2=0.f;
#pragma unroll
  for(int p=0;p<4;p++){ t[p]=x[tid+p*256]; s+=t[p]; s2+=t[p]*t[p]; }
  s=blockSum256(s,sc); s2=blockSum256(s2,sc);
  float mean=s/1024.f, rstd=rsqrtf(s2/1024.f-mean*mean+1e-5f);
#pragma unroll
  for(int p=0;p<4;p++){
    int h=tid+p*256;
    Y[(size_t)b*HH+h]=(t[p]-mean)*rstd*w[h]+bb[h];
  }
}

// ---------------- launch ----------------------------------------------------
extern "C" void kernel_launch(void* const* d_in, const int* in_sizes, int n_in,
                              void* d_out, int out_size, void* d_ws, size_t ws_size,
                              hipStream_t stream) {
  const float* tokens   =(const float*)d_in[0];
  const int*   mask     =(const int*)  d_in[1];
  const float* ln_go_w  =(const float*)d_in[2];
  const float* ln_go_b  =(const float*)d_in[3];
  const float* go_w1    =(const float*)d_in[4];
  const float* go_b1    =(const float*)d_in[5];
  const float* go_w2    =(const float*)d_in[6];
  const float* go_b2    =(const float*)d_in[7];
  const float* ln_ga_w  =(const float*)d_in[8];
  const float* ln_ga_b  =(const float*)d_in[9];
  const float* ga_w1    =(const float*)d_in[10];
  const float* ga_b1    =(const float*)d_in[11];
  const float* ga_w2    =(const float*)d_in[12];
  const float* ga_b2    =(const float*)d_in[13];
  const float* a2o_w    =(const float*)d_in[14];
  const float* o2a_w    =(const float*)d_in[15];
  const float* ln_o_w   =(const float*)d_in[16];
  const float* ln_o_b   =(const float*)d_in[17];
  const float* ln_a_w   =(const float*)d_in[18];
  const float* ln_a_b   =(const float*)d_in[19];
  const float* factors  =(const float*)d_in[20];
  const float* rank_w   =(const float*)d_in[21];
  const float* lmf_bias =(const float*)d_in[22];
  const float* out_ln1_w=(const float*)d_in[23];
  const float* out_ln1_b=(const float*)d_in[24];
  const float* out_w    =(const float*)d_in[25];
  const float* out_b    =(const float*)d_in[26];
  const float* out_ln2_w=(const float*)d_in[27];
  const float* out_ln2_b=(const float*)d_in[28];
  float* out=(float*)d_out;

  char* wsp=(char*)d_ws; size_t off=0;
  auto alloc=[&](size_t bytes)->void*{
    void* p=wsp+off; off=(off+bytes+255)&~(size_t)255; return p;
  };
  float*  P       =(float*) alloc((size_t)BB*RR*HH*4);      // 168 MB
  __bf16* factT   =(__bf16*)alloc((size_t)4*RR*HH*HH*2);    // 84 MB
  float*  H1      =(float*) alloc((size_t)BB*3*MIDD*4);
  float*  g_go    =(float*) alloc((size_t)BB*3*4);
  float*  a2o     =(float*) alloc((size_t)BB*HH*4);
  __bf16* mixedB  =(__bf16*)alloc((size_t)BB*4*HH*2);
  float*  omean   =(float*) alloc((size_t)BB*HH*4);
  __bf16* omeanB  =(__bf16*)alloc((size_t)BB*HH*2);
  __bf16* audioB  =(__bf16*)alloc((size_t)BB*HH*2);
  float*  H2      =(float*) alloc((size_t)BB*MIDD*4);
  float*  g_a     =(float*) alloc((size_t)BB*4);
  float*  o2a     =(float*) alloc((size_t)BB*HH*4);
  float*  fused   =(float*) alloc((size_t)BB*HH*4);
  __bf16* hbufB   =(__bf16*)alloc((size_t)BB*HH*2);
  __bf16* go_w1B  =(__bf16*)alloc((size_t)MIDD*D3*2);
  __bf16* ga_w1B  =(__bf16*)alloc((size_t)MIDD*D3*2);
  __bf16* a2o_wB  =(__bf16*)alloc((size_t)HH*HH*2);
  __bf16* o2a_wB  =(__bf16*)alloc((size_t)HH*HH*2);
  __bf16* out_wB  =(__bf16*)alloc((size_t)HH*HH*2);
  // feat buffers alias P (dead before lmf writes P): featGo 75.5MB + featGa 25.2MB < 168MB
  __bf16* featGo  =(__bf16*)P;
  __bf16* featGa  =(__bf16*)((char*)P + (size_t)BB*3*D3*2);

  // 0) weight converts + factor transpose (independent)
  {
    int n0=MIDD*D3, n1=MIDD*D3, n2=HH*HH, n3=HH*HH, n4=HH*HH;
    int total4=(n0+n1+n2+n3+n4)/4;
    convw_k<<<(total4+255)/256,256,0,stream>>>(go_w1,go_w1B,n0, ga_w1,ga_w1B,n1,
                                               a2o_w,a2o_wB,n2, o2a_w,o2a_wB,n3,
                                               out_w,out_wB,n4);
  }
  transpose_factors_k<<<dim3(16,16,40),256,0,stream>>>(factors,factT);
  // 1) gate-others features (bf16, LN applied) + audioB
  feat_go_k<<<BB*3,256,0,stream>>>(tokens,mask,ln_go_w,ln_go_b,featGo,audioB);
  // 2) a2o = audio @ a2o_w^T   (bf16 MFMA, 64x128 tiles)
  gemm_nt_mfma<0><<<dim3(8,64),256,0,stream>>>(audioB,HH,a2o_wB,HH,nullptr,a2o,HH,HH);
  // 3) H1 = gelu(featGo @ go_w1^T + go_b1)
  gemm_nt_mfma<1><<<dim3(4,192),256,0,stream>>>(featGo,D3,go_w1B,D3,go_b1,H1,MIDD,D3);
  // 4) g_go
  gate_reduce_k<<<BB*3,64,0,stream>>>(H1,go_w2,go_b2,g_go,MIDD);
  // 5) others_new -> mixedB {0,2,3}; others_mean (f32+bf16)
  others_k<<<BB,256,0,stream>>>(tokens,mask,g_go,a2o,ln_o_w,ln_o_b,mixedB,omean,omeanB);
  // 6) gate-audio features
  feat_ga_k<<<BB,256,0,stream>>>(tokens,omean,ln_ga_w,ln_ga_b,featGa);
  // 7) H2 = gelu(featGa @ ga_w1^T + ga_b1)
  gemm_nt_mfma<1><<<dim3(4,64),256,0,stream>>>(featGa,D3,ga_w1B,D3,ga_b1,H2,MIDD,D3);
  // 8) g_a
  gate_reduce_k<<<BB,64,0,stream>>>(H2,ga_w2,ga_b2,g_a,MIDD);
  // 9) o2a = others_mean @ o2a_w^T
  gemm_nt_mfma<0><<<dim3(8,64),256,0,stream>>>(omeanB,HH,o2a_wB,HH,nullptr,o2a,HH,HH);
  // 10) mixed_audio -> mixedB slot 1
  audio_k<<<BB,256,0,stream>>>(tokens,mask,g_a,o2a,ln_a_w,ln_a_b,mixedB);
  // 11) LMF rank product (MFMA, all m fused, pipelined, XCD-swizzled)
  gemm_lmf_mfma<<<dim3(HH/128,BB/128,RR),256,0,stream>>>(mixedB,factT,factors,mask,P);
  // 12+13) hbufB = LN(sum_r rank_w*P + lmf_bias)  (fused, one pass over P)
  fuse_ln_k<<<BB,256,0,stream>>>(P,rank_w,lmf_bias,out_ln1_w,out_ln1_b,hbufB);
  // 14) fused = gelu(hbufB @ out_w^T + out_b)
  gemm_nt_mfma<1><<<dim3(8,64),256,0,stream>>>(hbufB,HH,out_wB,HH,out_b,fused,HH,HH);
  // 15) out = LN(fused)
  ln_row_k<<<BB,256,0,stream>>>(fused,out_ln2_w,out_ln2_b,out);
}

// Round 5
// 1020.930 us; speedup vs baseline: 1.3867x; 1.0103x over previous
//
#include <hip/hip_runtime.h>
#include <math.h>

#define BB 4096
#define HH 1024
#define RR 10
#define MIDD 512
#define D3 3072

typedef __bf16 bf16x8 __attribute__((ext_vector_type(8)));
typedef __bf16 bf16x4 __attribute__((ext_vector_type(4)));
typedef float f32x4 __attribute__((ext_vector_type(4)));

// ---------------- reduction helpers ----------------
__device__ __forceinline__ float waveSum(float v){
#pragma unroll
  for(int o=32;o>0;o>>=1) v += __shfl_down(v,o,64);
  return v;
}
__device__ __forceinline__ float blockSum256(float v, float* sc){
  v = waveSum(v);
  __syncthreads();
  if((threadIdx.x & 63)==0) sc[threadIdx.x>>6] = v;
  __syncthreads();
  return sc[0]+sc[1]+sc[2]+sc[3];
}
__device__ __forceinline__ float gelu_f(float x){
  return 0.5f*x*(1.0f+erff(x*0.70710678118654752f));
}
__device__ __forceinline__ void gl_lds16(const void* g, void* lds){
  __builtin_amdgcn_global_load_lds((const __attribute__((address_space(1))) unsigned int*)g,
                                   (__attribute__((address_space(3))) unsigned int*)lds,
                                   16, 0, 0);
}

// ---------- weight convert: 5 fp32 matrices -> bf16, one launch -------------
__global__ void convw_k(const float* __restrict__ s0, __bf16* __restrict__ d0, int n0,
                        const float* __restrict__ s1, __bf16* __restrict__ d1, int n1,
                        const float* __restrict__ s2, __bf16* __restrict__ d2, int n2,
                        const float* __restrict__ s3, __bf16* __restrict__ d3, int n3,
                        const float* __restrict__ s4, __bf16* __restrict__ d4, int n4){
  long i = ((long)blockIdx.x*256 + threadIdx.x)*4;
  const float* s; __bf16* d;
  if(i<n0){ s=s0; d=d0; }
  else { i-=n0; if(i<n1){ s=s1; d=d1; }
  else { i-=n1; if(i<n2){ s=s2; d=d2; }
  else { i-=n2; if(i<n3){ s=s3; d=d3; }
  else { i-=n3; if(i>=n4) return; s=s4; d=d4; } } } }
  float4 v=*(const float4*)(s+i);
  bf16x4 o; o[0]=(__bf16)v.x; o[1]=(__bf16)v.y; o[2]=(__bf16)v.z; o[3]=(__bf16)v.w;
  *(bf16x4*)(d+i)=o;
}

// ------- gate-others features: LN([t,s,|t-s|]) -> bf16 rows (B*3 x 3072) ----
// also writes audioB; zeroes g_pre[row] for the H1 gate-atomic GEMM.
__global__ void feat_go_k(const float* __restrict__ tokens, const int* __restrict__ mask,
                          const float* __restrict__ lnw, const float* __restrict__ lnb,
                          __bf16* __restrict__ featGo, __bf16* __restrict__ audioB,
                          float* __restrict__ gpre){
  int row=blockIdx.x; int b=row/3; int j=row-b*3; int oj=(j==0)?0:(j+1);
  if(threadIdx.x==0) gpre[row]=0.f;
  const float* to=tokens+((size_t)b*4+oj)*HH;
  const float* ta=tokens+((size_t)b*4+1)*HH;
  float mo = mask[b*4+oj]?1.f:0.f;
  int tid=threadIdx.x;
  __shared__ float sc[4];
  float ov[4], av[4], dv[4]; float s=0.f,s2=0.f;
#pragma unroll
  for(int p=0;p<4;p++){
    int h=tid+p*256;
    float o=to[h]*mo, a=ta[h], d=fabsf(o-a);
    ov[p]=o; av[p]=a; dv[p]=d;
    s+=o+a+d; s2+=o*o+a*a+d*d;
  }
  s=blockSum256(s,sc); s2=blockSum256(s2,sc);
  float mean=s/(float)D3, rstd=rsqrtf(s2/(float)D3-mean*mean+1e-5f);
  __bf16* fr = featGo + (size_t)row*D3;
#pragma unroll
  for(int p=0;p<4;p++){
    int h=tid+p*256;
    fr[h]       =(__bf16)((ov[p]-mean)*rstd*lnw[h]+lnb[h]);
    fr[1024+h]  =(__bf16)((av[p]-mean)*rstd*lnw[1024+h]+lnb[1024+h]);
    fr[2048+h]  =(__bf16)((dv[p]-mean)*rstd*lnw[2048+h]+lnb[2048+h]);
    if(j==0) audioB[(size_t)b*HH+h]=(__bf16)av[p];
  }
}

// -------- unified bf16 MFMA NT GEMM ----------------------------------------
// ACT=0: C=A@B^T.  ACT=1: C=gelu(A@B^T+bias).
// ACT=2: no C store; atomicAdd(gpre[row], sum_col gelu(v+bias[col])*w2[col]).
// 64x128 tile, BK=32, 4 waves, 3-buf depth-2 counted-vmcnt(3), XCD swizzle.
template<int ACT>
__launch_bounds__(256, 4)
__global__ void gemm_nt_mfma(const __bf16* __restrict__ A, int lda,
                             const __bf16* __restrict__ Bm, int ldb,
                             const float* __restrict__ bias,
                             float* __restrict__ C, int ldc, int K,
                             const float* __restrict__ w2,
                             float* __restrict__ gpre){
  __shared__ __align__(16) __bf16 As[3*2048];   // 3 bufs x 64x32
  __shared__ __align__(16) __bf16 Bs[3*4096];   // 3 bufs x 128x32
  const int tid=threadIdx.x, l=tid&63, w=tid>>6;
  const int wr=w>>1, wc=w&1;
  const int quad=l>>4, lr16=l&15;

  const int nbx = gridDim.x;
  const int flat = blockIdx.x + nbx*blockIdx.y;
  const int chunk = (nbx*gridDim.y)>>3;
  const int nid = (flat&7)*chunk + (flat>>3);
  const int bx = nid % nbx, by = nid / nbx;
  const int row0=by*64, col0=bx*128;

  const int srow=l>>2, sq=(l&3)^((l>>3)&3);
  const int nsteps = K>>5;

  const __bf16* pa  = A  + (size_t)(row0 + w*16       + srow)*lda + sq*8;
  const __bf16* pb0 = Bm + (size_t)(col0 + w*16       + srow)*ldb + sq*8;
  const __bf16* pb1 = Bm + (size_t)(col0 + (w+4)*16   + srow)*ldb + sq*8;
  __bf16* da  = As + ((size_t)w*64     + l)*8;
  __bf16* db0 = Bs + ((size_t)w*64     + l)*8;
  __bf16* db1 = Bs + ((size_t)(w+4)*64 + l)*8;

  auto stage=[&](int s,int bi){
    int k0 = s*32;
    gl_lds16(pa  + k0, da  + bi*2048);
    gl_lds16(pb0 + k0, db0 + bi*4096);
    gl_lds16(pb1 + k0, db1 + bi*4096);
  };

  f32x4 acc[2][4];
  f32x4 zerov={0.f,0.f,0.f,0.f};
#pragma unroll
  for(int i=0;i<2;i++)
#pragma unroll
    for(int j=0;j<4;j++) acc[i][j]=zerov;

  stage(0,0);
  stage(1,1);
  asm volatile("s_waitcnt vmcnt(3)" ::: "memory");
  __builtin_amdgcn_s_barrier();

  int cur=0;
  for(int step=0; step<nsteps; ++step){
    const __bf16* Ab = As + cur*2048;
    const __bf16* Bb = Bs + cur*4096;
    bf16x8 af[2], bg[4];
#pragma unroll
    for(int fi=0;fi<2;fi++){
      int R = wr*32 + fi*16 + lr16;
      af[fi]=*(const bf16x8*)(Ab + R*32 + ((quad^(R>>1))&3)*8);
    }
#pragma unroll
    for(int fj=0;fj<4;fj++){
      int N = wc*64 + fj*16 + lr16;
      bg[fj]=*(const bf16x8*)(Bb + N*32 + ((quad^(N>>1))&3)*8);
    }
    if(step+2<nsteps){
      int bi = cur + 2; if(bi>=3) bi-=3;
      stage(step+2, bi);
    }
    __builtin_amdgcn_s_setprio(1);
#pragma unroll
    for(int fi=0;fi<2;fi++)
#pragma unroll
      for(int fj=0;fj<4;fj++)
        acc[fi][fj]=__builtin_amdgcn_mfma_f32_16x16x32_bf16(af[fi],bg[fj],acc[fi][fj],0,0,0);
    __builtin_amdgcn_s_setprio(0);
    asm volatile("s_waitcnt lgkmcnt(0)" ::: "memory");
    if(step < nsteps-2) asm volatile("s_waitcnt vmcnt(3)" ::: "memory");
    else                asm volatile("s_waitcnt vmcnt(0)" ::: "memory");
    __builtin_amdgcn_s_barrier();
    cur = (cur+1==3)?0:cur+1;
  }

  if(ACT==2){
    float b1v[4], w2v[4];
#pragma unroll
    for(int fj=0;fj<4;fj++){
      int col=col0+wc*64+fj*16+lr16;
      b1v[fj]=bias[col]; w2v[fj]=w2[col];
    }
#pragma unroll
    for(int fi=0;fi<2;fi++){
#pragma unroll
      for(int reg=0;reg<4;reg++){
        float part=0.f;
#pragma unroll
        for(int fj=0;fj<4;fj++) part += gelu_f(acc[fi][fj][reg]+b1v[fj])*w2v[fj];
        part += __shfl_xor(part,1,64);
        part += __shfl_xor(part,2,64);
        part += __shfl_xor(part,4,64);
        part += __shfl_xor(part,8,64);
        if((l&15)==0) atomicAdd(&gpre[row0+wr*32+fi*16+quad*4+reg], part);
      }
    }
    return;
  }

  float bv[4];
#pragma unroll
  for(int fj=0;fj<4;fj++) bv[fj] = (ACT==1)? bias[col0+wc*64+fj*16+lr16] : 0.f;
#pragma unroll
  for(int fi=0;fi<2;fi++){
#pragma unroll
    for(int reg=0;reg<4;reg++){
      int row=row0+wr*32+fi*16+quad*4+reg;
#pragma unroll
      for(int fj=0;fj<4;fj++){
        int col=col0+wc*64+fj*16+lr16;
        float v=acc[fi][fj][reg];
        if(ACT==1) v=gelu_f(v+bv[fj]);
        C[(size_t)row*ldc+col]=v;
      }
    }
  }
}

// ------- others_new (mixedB 0,2,3) + omeanB + fused feat_ga + ga_pre=0 ------
__global__ void others_k(const float* __restrict__ tokens, const int* __restrict__ mask,
                         const float* __restrict__ gpre, const float* __restrict__ go_b2,
                         const float* __restrict__ a2o,
                         const float* __restrict__ lnw, const float* __restrict__ lnb,
                         const float* __restrict__ galnw, const float* __restrict__ galnb,
                         __bf16* __restrict__ mixedB, __bf16* __restrict__ omeanB,
                         __bf16* __restrict__ featGa, float* __restrict__ gapre){
  int b=blockIdx.x, tid=threadIdx.x;
  __shared__ float sc[4];
  if(tid==0) gapre[b]=0.f;
  float ma = mask[b*4+1]?1.f:0.f;
  float a2[4];
#pragma unroll
  for(int p=0;p<4;p++) a2[p]=a2o[(size_t)b*HH+tid+p*256];
  float sum[4]={0,0,0,0}; float cnt=0.f;
  for(int j=0;j<3;j++){
    int oj=(j==0)?0:(j+1);
    float mo=mask[b*4+oj]?1.f:0.f; cnt+=mo;
    float gv=1.f/(1.f+expf(-(gpre[b*3+j]+go_b2[0])));
    float t[4], ov[4]; float s=0.f,s2=0.f;
#pragma unroll
    for(int p=0;p<4;p++){
      int h=tid+p*256;
      float o=tokens[((size_t)b*4+oj)*HH+h]*mo;
      ov[p]=o; t[p]=o+gv*a2[p];
      s+=t[p]; s2+=t[p]*t[p];
    }
    s=blockSum256(s,sc); s2=blockSum256(s2,sc);
    float mean=s/1024.f, rstd=rsqrtf(s2/1024.f-mean*mean+1e-5f);
    float pv=mo*ma;
#pragma unroll
    for(int p=0;p<4;p++){
      int h=tid+p*256;
      float upd=(t[p]-mean)*rstd*lnw[h]+lnb[h];
      float on=((pv>0.5f)?upd:ov[p])*mo;
      mixedB[(size_t)b*4096 + (size_t)oj*HH + h]=(__bf16)on;
      sum[p]+=on*mo;
    }
  }
  float denom=fmaxf(cnt,1.f);
  float vm[4];
#pragma unroll
  for(int p=0;p<4;p++){
    vm[p]=sum[p]/denom;
    omeanB[(size_t)b*HH+tid+p*256]=(__bf16)vm[p];
  }
  // ---- fused gate-audio features: LN([audio, omean, |diff|]) ----
  const float* ta=tokens+((size_t)b*4+1)*HH;
  float tv[4], dv[4]; float s=0.f,s2=0.f;
#pragma unroll
  for(int p=0;p<4;p++){
    int h=tid+p*256;
    float a=ta[h], d=fabsf(a-vm[p]);
    tv[p]=a; dv[p]=d;
    s+=a+vm[p]+d; s2+=a*a+vm[p]*vm[p]+d*d;
  }
  s=blockSum256(s,sc); s2=blockSum256(s2,sc);
  float mean=s/(float)D3, rstd=rsqrtf(s2/(float)D3-mean*mean+1e-5f);
  __bf16* fr=featGa+(size_t)b*D3;
#pragma unroll
  for(int p=0;p<4;p++){
    int h=tid+p*256;
    fr[h]     =(__bf16)((tv[p]-mean)*rstd*galnw[h]+galnb[h]);
    fr[1024+h]=(__bf16)((vm[p]-mean)*rstd*galnw[1024+h]+galnb[1024+h]);
    fr[2048+h]=(__bf16)((dv[p]-mean)*rstd*galnw[2048+h]+galnb[2048+h]);
  }
}

// ------- mixed_audio (mixedB slot 1) + fused init to lmf_bias ---------------
__global__ void audio_k(const float* __restrict__ tokens, const int* __restrict__ mask,
                        const float* __restrict__ gapre, const float* __restrict__ ga_b2,
                        const float* __restrict__ o2a,
                        const float* __restrict__ lnw, const float* __restrict__ lnb,
                        __bf16* __restrict__ mixedB,
                        const float* __restrict__ lmf_bias, float* __restrict__ fused){
  int b=blockIdx.x, tid=threadIdx.x;
  __shared__ float sc[4];
  int ma_i=mask[b*4+1];
  int any = mask[b*4+0]|mask[b*4+2]|mask[b*4+3];
  bool aum = (ma_i!=0) && (any!=0);
  float ma = ma_i?1.f:0.f;
  float gv=1.f/(1.f+expf(-(gapre[b]+ga_b2[0])));
  const float* ta = tokens + ((size_t)b*4+1)*HH;
  float av[4], t[4]; float s=0.f,s2=0.f;
#pragma unroll
  for(int p=0;p<4;p++){
    int h=tid+p*256;
    av[p]=ta[h];
    t[p]=av[p]+gv*o2a[(size_t)b*HH+h];
    s+=t[p]; s2+=t[p]*t[p];
  }
  s=blockSum256(s,sc); s2=blockSum256(s2,sc);
  float mean=s/1024.f, rstd=rsqrtf(s2/1024.f-mean*mean+1e-5f);
#pragma unroll
  for(int p=0;p<4;p++){
    int h=tid+p*256;
    float u=(t[p]-mean)*rstd*lnw[h]+lnb[h];
    float outv = aum ? u : av[p]*ma;
    mixedB[(size_t)b*4096 + HH + h]=(__bf16)(outv*ma);
    fused[(size_t)b*HH + h]=lmf_bias[h];
  }
}

// ------- factors [mr][1025][1024] fp32 -> factT [mr][h][d] bf16 (d=1..1024) -
__global__ void transpose_factors_k(const float* __restrict__ factors,
                                    __bf16* __restrict__ factT){
  __shared__ float T[64][65];
  int mr = blockIdx.z;
  int d0 = blockIdx.y*64, h0 = blockIdx.x*64;
  int t = threadIdx.x;
  int rr = t>>4, cc = (t&15)*4;
  const float* src = factors + ((size_t)mr*1025 + 1 + d0)*1024 + h0;
#pragma unroll
  for(int q=0;q<4;q++){
    float4 v = *(const float4*)(src + (size_t)(q*16+rr)*1024 + cc);
    T[q*16+rr][cc]=v.x; T[q*16+rr][cc+1]=v.y; T[q*16+rr][cc+2]=v.z; T[q*16+rr][cc+3]=v.w;
  }
  __syncthreads();
  __bf16* dst = factT + ((size_t)mr*1024 + h0)*1024 + d0;
#pragma unroll
  for(int q=0;q<4;q++){
    int hr = q*16 + rr;
    bf16x4 o;
    o[0]=(__bf16)T[cc][hr];   o[1]=(__bf16)T[cc+1][hr];
    o[2]=(__bf16)T[cc+2][hr]; o[3]=(__bf16)T[cc+3][hr];
    *(bf16x4*)(dst + (size_t)hr*1024 + cc) = o;
  }
}

// -------- LMF: fused[b,h] += sum_{r in half} rank_w[r]*prod_m(mask? z : 1) --
// r INSIDE the block (5 per z-half): P buffer eliminated entirely.
// 128x128 tile, 640 K-steps, 3-buf depth-2 counted-vmcnt(4) pipeline.
// Grid (8,32,2)=512 blocks; swizzle pins each h-tile to one XCD.
__launch_bounds__(256, 2)
__global__ void gemm_lmf2(const __bf16* __restrict__ mixedB,
                          const __bf16* __restrict__ factT,
                          const float* __restrict__ factors,
                          const int* __restrict__ mask,
                          const float* __restrict__ rank_w,
                          float* __restrict__ fused){
  __shared__ __align__(16) __bf16 As[3*4096];   // 3 bufs x 128x32
  __shared__ __align__(16) __bf16 Bs[3*4096];
  __shared__ float Mskf[4][128];
  __shared__ float F0s[20][128];                // [rm = rloc*4+m][col]
  __shared__ float Rws[5];
  const int tid = threadIdx.x;
  const int l = tid & 63, w = tid >> 6;
  const int wr = w >> 1, wc = w & 1;
  const int quad = l >> 4, lr16 = l & 15;

  // swizzle: XCD c <- h-tile c (B-panel L2-resident per XCD)
  const int flat = blockIdx.x + 8*(blockIdx.y + 32*blockIdx.z);
  const int nid  = (flat & 7)*64 + (flat >> 3);
  const int hh   = nid >> 6;
  const int rest = nid & 63;
  const int by   = rest >> 1;
  const int bz   = rest & 1;
  const int row0 = by * 128, col0 = hh * 128;
  const int z5   = bz * 5;

  const int srow = l >> 2;
  const int sq   = (l & 3) ^ ((l >> 3) & 3);

  // ---- prologue: masks + F0 rows + rank_w into LDS ----
  for(int i = tid; i < 512; i += 256){
    int mm = i >> 7, rl = i & 127;
    Mskf[mm][rl] = mask[(row0 + rl)*4 + mm] ? 1.f : 0.f;
  }
  for(int i = tid; i < 2560; i += 256){
    int rm = i >> 7, cl = i & 127;
    int m = rm & 3, rg = z5 + (rm >> 2);
    F0s[rm][cl] = factors[(size_t)(m*RR + rg)*1025*1024 + col0 + cl];
  }
  if(tid < 5) Rws[tid] = rank_w[z5 + tid];

  const __bf16* pa0 = mixedB + (size_t)(row0 + w*16     + srow)*4096 + sq*8;
  const __bf16* pa1 = mixedB + (size_t)(row0 + (w+4)*16 + srow)*4096 + sq*8;
  const __bf16* pb0 = factT + ((size_t)(col0 + w*16     + srow))*1024 + sq*8;
  const __bf16* pb1 = factT + ((size_t)(col0 + (w+4)*16 + srow))*1024 + sq*8;
  __bf16* da0 = As + ((size_t)w*64     + l)*8;
  __bf16* da1 = As + ((size_t)(w+4)*64 + l)*8;
  __bf16* db0 = Bs + ((size_t)w*64     + l)*8;
  __bf16* db1 = Bs + ((size_t)(w+4)*64 + l)*8;

  auto stage = [&](int s, int bi){
    int rm = s >> 5, k0 = (s & 31)*32;
    int m = rm & 3, rg = z5 + (rm >> 2);
    size_t ao = (size_t)m*1024 + k0;
    size_t bo = (size_t)(m*RR + rg)*1048576 + k0;
    gl_lds16(pa0 + ao, da0 + bi*4096);
    gl_lds16(pa1 + ao, da1 + bi*4096);
    gl_lds16(pb0 + bo, db0 + bi*4096);
    gl_lds16(pb1 + bo, db1 + bi*4096);
  };

  f32x4 fsum[4][4];
  f32x4 prod[4][4];
  f32x4 acc[4][4];
  f32x4 zerov = {0.f,0.f,0.f,0.f};
#pragma unroll
  for(int i=0;i<4;i++)
#pragma unroll
    for(int j=0;j<4;j++) fsum[i][j] = zerov;

  stage(0, 0);
  stage(1, 1);
  asm volatile("s_waitcnt vmcnt(4)" ::: "memory");
  asm volatile("s_waitcnt lgkmcnt(0)" ::: "memory");   // LDS prologue visible
  __builtin_amdgcn_s_barrier();

  int cur = 0;
  for(int step = 0; step < 640; ++step){
    const __bf16* Ab = As + cur*4096;
    const __bf16* Bb = Bs + cur*4096;
    bf16x8 af[4], bg[4];
#pragma unroll
    for(int fi=0;fi<4;fi++){
      int R = wr*64 + fi*16 + lr16;
      af[fi] = *(const bf16x8*)(Ab + R*32 + ((quad ^ (R>>1)) & 3)*8);
    }
#pragma unroll
    for(int fj=0;fj<4;fj++){
      int N = wc*64 + fj*16 + lr16;
      bg[fj] = *(const bf16x8*)(Bb + N*32 + ((quad ^ (N>>1)) & 3)*8);
    }
    if(step + 2 < 640){
      int bi = cur + 2; if(bi >= 3) bi -= 3;
      stage(step + 2, bi);
    }
    if((step & 127) == 0){
      f32x4 onev = {1.f,1.f,1.f,1.f};
#pragma unroll
      for(int fi=0;fi<4;fi++)
#pragma unroll
        for(int fj=0;fj<4;fj++) prod[fi][fj] = onev;
    }
    if((step & 31) == 0){
      int rm = step >> 5;
#pragma unroll
      for(int fj=0;fj<4;fj++){
        float f0 = F0s[rm][wc*64 + fj*16 + lr16];
        f32x4 iv = {f0,f0,f0,f0};
#pragma unroll
        for(int fi=0;fi<4;fi++) acc[fi][fj] = iv;
      }
    }
    __builtin_amdgcn_s_setprio(1);
#pragma unroll
    for(int fi=0;fi<4;fi++)
#pragma unroll
      for(int fj=0;fj<4;fj++)
        acc[fi][fj] = __builtin_amdgcn_mfma_f32_16x16x32_bf16(af[fi], bg[fj], acc[fi][fj], 0,0,0);
    __builtin_amdgcn_s_setprio(0);
    if((step & 31) == 31){
      int mm = (step >> 5) & 3;
#pragma unroll
      for(int fi=0;fi<4;fi++)
#pragma unroll
        for(int reg=0;reg<4;reg++){
          float mk = Mskf[mm][wr*64 + fi*16 + quad*4 + reg];
#pragma unroll
          for(int fj=0;fj<4;fj++)
            prod[fi][fj][reg] *= (mk != 0.f) ? acc[fi][fj][reg] : 1.f;
        }
    }
    if((step & 127) == 127){
      float rw = Rws[step >> 7];
#pragma unroll
      for(int fi=0;fi<4;fi++)
#pragma unroll
        for(int fj=0;fj<4;fj++)
#pragma unroll
          for(int reg=0;reg<4;reg++)
            fsum[fi][fj][reg] += rw * prod[fi][fj][reg];
    }
    asm volatile("s_waitcnt lgkmcnt(0)" ::: "memory");
    if(step < 638) asm volatile("s_waitcnt vmcnt(4)" ::: "memory");
    else           asm volatile("s_waitcnt vmcnt(0)" ::: "memory");
    __builtin_amdgcn_s_barrier();
    cur = (cur + 1 == 3) ? 0 : cur + 1;
  }

#pragma unroll
  for(int fi=0;fi<4;fi++){
#pragma unroll
    for(int reg=0;reg<4;reg++){
      int row = row0 + wr*64 + fi*16 + quad*4 + reg;
#pragma unroll
      for(int fj=0;fj<4;fj++){
        int col = col0 + wc*64 + fj*16 + lr16;
        atomicAdd(&fused[(size_t)row*HH + col], fsum[fi][fj][reg]);
      }
    }
  }
}

// ---------------- row LayerNorm over H=1024 (fp32 out) ----------------------
__global__ void ln_row_k(const float* __restrict__ X, const float* __restrict__ w,
                         const float* __restrict__ bb, float* __restrict__ Y){
  int b=blockIdx.x, tid=threadIdx.x;
  __shared__ float sc[4];
  const float* x=X+(size_t)b*HH;
  float t[4]; float s=0.f,s2=0.f;
#pragma unroll
  for(int p=0;p<4;p++){ t[p]=x[tid+p*256]; s+=t[p]; s2+=t[p]*t[p]; }
  s=blockSum256(s,sc); s2=blockSum256(s2,sc);
  float mean=s/1024.f, rstd=rsqrtf(s2/1024.f-mean*mean+1e-5f);
#pragma unroll
  for(int p=0;p<4;p++){
    int h=tid+p*256;
    Y[(size_t)b*HH+h]=(t[p]-mean)*rstd*w[h]+bb[h];
  }
}
// ---------------- row LayerNorm over H=1024 (bf16 out) ----------------------
__global__ void ln_row_bf16_k(const float* __restrict__ X, const float* __restrict__ w,
                              const float* __restrict__ bb, __bf16* __restrict__ Y){
  int b=blockIdx.x, tid=threadIdx.x;
  __shared__ float sc[4];
  const float* x=X+(size_t)b*HH;
  float t[4]; float s=0.f,s2=0.f;
#pragma unroll
  for(int p=0;p<4;p++){ t[p]=x[tid+p*256]; s+=t[p]; s2+=t[p]*t[p]; }
  s=blockSum256(s,sc); s2=blockSum256(s2,sc);
  float mean=s/1024.f, rstd=rsqrtf(s2/1024.f-mean*mean+1e-5f);
#pragma unroll
  for(int p=0;p<4;p++){
    int h=tid+p*256;
    Y[(size_t)b*HH+h]=(__bf16)((t[p]-mean)*rstd*w[h]+bb[h]);
  }
}

// ---------------- launch ----------------------------------------------------
extern "C" void kernel_launch(void* const* d_in, const int* in_sizes, int n_in,
                              void* d_out, int out_size, void* d_ws, size_t ws_size,
                              hipStream_t stream) {
  const float* tokens   =(const float*)d_in[0];
  const int*   mask     =(const int*)  d_in[1];
  const float* ln_go_w  =(const float*)d_in[2];
  const float* ln_go_b  =(const float*)d_in[3];
  const float* go_w1    =(const float*)d_in[4];
  const float* go_b1    =(const float*)d_in[5];
  const float* go_w2    =(const float*)d_in[6];
  const float* go_b2    =(const float*)d_in[7];
  const float* ln_ga_w  =(const float*)d_in[8];
  const float* ln_ga_b  =(const float*)d_in[9];
  const float* ga_w1    =(const float*)d_in[10];
  const float* ga_b1    =(const float*)d_in[11];
  const float* ga_w2    =(const float*)d_in[12];
  const float* ga_b2    =(const float*)d_in[13];
  const float* a2o_w    =(const float*)d_in[14];
  const float* o2a_w    =(const float*)d_in[15];
  const float* ln_o_w   =(const float*)d_in[16];
  const float* ln_o_b   =(const float*)d_in[17];
  const float* ln_a_w   =(const float*)d_in[18];
  const float* ln_a_b   =(const float*)d_in[19];
  const float* factors  =(const float*)d_in[20];
  const float* rank_w   =(const float*)d_in[21];
  const float* lmf_bias =(const float*)d_in[22];
  const float* out_ln1_w=(const float*)d_in[23];
  const float* out_ln1_b=(const float*)d_in[24];
  const float* out_w    =(const float*)d_in[25];
  const float* out_b    =(const float*)d_in[26];
  const float* out_ln2_w=(const float*)d_in[27];
  const float* out_ln2_b=(const float*)d_in[28];
  float* out=(float*)d_out;

  char* wsp=(char*)d_ws; size_t off=0;
  auto alloc=[&](size_t bytes)->void*{
    void* p=wsp+off; off=(off+bytes+255)&~(size_t)255; return p;
  };
  __bf16* factT   =(__bf16*)alloc((size_t)4*RR*HH*HH*2);    // 84 MB
  __bf16* featGo  =(__bf16*)alloc((size_t)BB*3*D3*2);       // 75.5 MB
  __bf16* featGa  =(__bf16*)alloc((size_t)BB*D3*2);         // 25.2 MB
  float*  g_go_pre=(float*) alloc((size_t)BB*3*4);
  float*  ga_pre  =(float*) alloc((size_t)BB*4);
  float*  a2o     =(float*) alloc((size_t)BB*HH*4);
  __bf16* mixedB  =(__bf16*)alloc((size_t)BB*4*HH*2);
  __bf16* omeanB  =(__bf16*)alloc((size_t)BB*HH*2);
  __bf16* audioB  =(__bf16*)alloc((size_t)BB*HH*2);
  float*  o2a     =(float*) alloc((size_t)BB*HH*4);
  float*  fused   =(float*) alloc((size_t)BB*HH*4);
  __bf16* hbufB   =(__bf16*)alloc((size_t)BB*HH*2);
  __bf16* go_w1B  =(__bf16*)alloc((size_t)MIDD*D3*2);
  __bf16* ga_w1B  =(__bf16*)alloc((size_t)MIDD*D3*2);
  __bf16* a2o_wB  =(__bf16*)alloc((size_t)HH*HH*2);
  __bf16* o2a_wB  =(__bf16*)alloc((size_t)HH*HH*2);
  __bf16* out_wB  =(__bf16*)alloc((size_t)HH*HH*2);

  // 0) weight converts + factor transpose (independent)
  {
    int n0=MIDD*D3, n1=MIDD*D3, n2=HH*HH, n3=HH*HH, n4=HH*HH;
    int total4=(n0+n1+n2+n3+n4)/4;
    convw_k<<<(total4+255)/256,256,0,stream>>>(go_w1,go_w1B,n0, ga_w1,ga_w1B,n1,
                                               a2o_w,a2o_wB,n2, o2a_w,o2a_wB,n3,
                                               out_w,out_wB,n4);
  }
  transpose_factors_k<<<dim3(16,16,40),256,0,stream>>>(factors,factT);
  // 1) gate-others features + audioB + g_go_pre=0
  feat_go_k<<<BB*3,256,0,stream>>>(tokens,mask,ln_go_w,ln_go_b,featGo,audioB,g_go_pre);
  // 2) a2o = audio @ a2o_w^T
  gemm_nt_mfma<0><<<dim3(8,64),256,0,stream>>>(audioB,HH,a2o_wB,HH,nullptr,a2o,HH,HH,nullptr,nullptr);
  // 3) gate-others MLP fully fused: g_go_pre += gelu(featGo@go_w1^T+go_b1).go_w2
  gemm_nt_mfma<2><<<dim3(4,192),256,0,stream>>>(featGo,D3,go_w1B,D3,go_b1,nullptr,0,D3,go_w2,g_go_pre);
  // 4) others_new + omeanB + featGa + ga_pre=0 (sigmoid of g_go_pre inside)
  others_k<<<BB,256,0,stream>>>(tokens,mask,g_go_pre,go_b2,a2o,ln_o_w,ln_o_b,
                                ln_ga_w,ln_ga_b,mixedB,omeanB,featGa,ga_pre);
  // 5) gate-audio MLP fully fused -> ga_pre
  gemm_nt_mfma<2><<<dim3(4,64),256,0,stream>>>(featGa,D3,ga_w1B,D3,ga_b1,nullptr,0,D3,ga_w2,ga_pre);
  // 6) o2a = others_mean @ o2a_w^T
  gemm_nt_mfma<0><<<dim3(8,64),256,0,stream>>>(omeanB,HH,o2a_wB,HH,nullptr,o2a,HH,HH,nullptr,nullptr);
  // 7) mixed_audio -> mixedB slot 1; fused init to lmf_bias
  audio_k<<<BB,256,0,stream>>>(tokens,mask,ga_pre,ga_b2,o2a,ln_a_w,ln_a_b,mixedB,lmf_bias,fused);
  // 8) LMF: r-inside, atomic accumulate into fused (no P buffer)
  gemm_lmf2<<<dim3(8,32,2),256,0,stream>>>(mixedB,factT,factors,mask,rank_w,fused);
  // 9) hbufB = LN(fused) as bf16
  ln_row_bf16_k<<<BB,256,0,stream>>>(fused,out_ln1_w,out_ln1_b,hbufB);
  // 10) fused = gelu(hbufB @ out_w^T + out_b)
  gemm_nt_mfma<1><<<dim3(8,64),256,0,stream>>>(hbufB,HH,out_wB,HH,out_b,fused,HH,HH,nullptr,nullptr);
  // 11) out = LN(fused)
  ln_row_k<<<BB,256,0,stream>>>(fused,out_ln2_w,out_ln2_b,out);
}

// Round 6
// 1010.145 us; speedup vs baseline: 1.4015x; 1.0107x over previous
//
#include <hip/hip_runtime.h>
#include <math.h>

#define BB 4096
#define HH 1024
#define RR 10
#define MIDD 512
#define D3 3072

typedef __bf16 bf16x8 __attribute__((ext_vector_type(8)));
typedef __bf16 bf16x4 __attribute__((ext_vector_type(4)));
typedef float f32x4 __attribute__((ext_vector_type(4)));

// ---------------- reduction helpers ----------------
__device__ __forceinline__ float waveSum(float v){
#pragma unroll
  for(int o=32;o>0;o>>=1) v += __shfl_down(v,o,64);
  return v;
}
__device__ __forceinline__ float blockSum256(float v, float* sc){
  v = waveSum(v);
  __syncthreads();
  if((threadIdx.x & 63)==0) sc[threadIdx.x>>6] = v;
  __syncthreads();
  return sc[0]+sc[1]+sc[2]+sc[3];
}
__device__ __forceinline__ float gelu_f(float x){
  return 0.5f*x*(1.0f+erff(x*0.70710678118654752f));
}
__device__ __forceinline__ void gl_lds16(const void* g, void* lds){
  __builtin_amdgcn_global_load_lds((const __attribute__((address_space(1))) unsigned int*)g,
                                   (__attribute__((address_space(3))) unsigned int*)lds,
                                   16, 0, 0);
}

// ================= prep_k: convw + transpose_factors + feat_go ==============
// blocks [0,6144): weight converts; [6144,16384): factor transpose;
// [16384,28672): gate-others features (+audioB, gpre=0).
__global__ void prep_k(const float* __restrict__ go_w1, __bf16* __restrict__ go_w1B,
                       const float* __restrict__ ga_w1, __bf16* __restrict__ ga_w1B,
                       const float* __restrict__ a2o_w, __bf16* __restrict__ a2o_wB,
                       const float* __restrict__ o2a_w, __bf16* __restrict__ o2a_wB,
                       const float* __restrict__ out_w, __bf16* __restrict__ out_wB,
                       const float* __restrict__ factors, __bf16* __restrict__ factT,
                       const float* __restrict__ tokens, const int* __restrict__ mask,
                       const float* __restrict__ lnw, const float* __restrict__ lnb,
                       __bf16* __restrict__ featGo, __bf16* __restrict__ audioB,
                       float* __restrict__ gpre){
  __shared__ float T[64][65];   // transpose tile; feat_go reuses T[0][0..3] as sc
  const int b = blockIdx.x;
  const int tid = threadIdx.x;

  if(b < 6144){
    // ---- weight convert: 5 matrices, flat range dispatch ----
    const int n0=MIDD*D3, n1=MIDD*D3, n2=HH*HH, n3=HH*HH, n4=HH*HH;
    long i = ((long)b*256 + tid)*4;
    const float* s; __bf16* d;
    if(i<n0){ s=go_w1; d=go_w1B; }
    else { i-=n0; if(i<n1){ s=ga_w1; d=ga_w1B; }
    else { i-=n1; if(i<n2){ s=a2o_w; d=a2o_wB; }
    else { i-=n2; if(i<n3){ s=o2a_w; d=o2a_wB; }
    else { i-=n3; if(i>=n4) return; s=out_w; d=out_wB; } } } }
    float4 v=*(const float4*)(s+i);
    bf16x4 o; o[0]=(__bf16)v.x; o[1]=(__bf16)v.y; o[2]=(__bf16)v.z; o[3]=(__bf16)v.w;
    *(bf16x4*)(d+i)=o;
    return;
  }
  if(b < 16384){
    // ---- factors [mr][1025][1024] fp32 -> factT [mr][h][d] bf16 ----
    int id = b - 6144;
    int h0 = (id & 15)*64;
    int d0 = ((id >> 4) & 15)*64;
    int mr = id >> 8;
    int rr = tid>>4, cc = (tid&15)*4;
    const float* src = factors + ((size_t)mr*1025 + 1 + d0)*1024 + h0;
#pragma unroll
    for(int q=0;q<4;q++){
      float4 v = *(const float4*)(src + (size_t)(q*16+rr)*1024 + cc);
      T[q*16+rr][cc]=v.x; T[q*16+rr][cc+1]=v.y; T[q*16+rr][cc+2]=v.z; T[q*16+rr][cc+3]=v.w;
    }
    __syncthreads();
    __bf16* dst = factT + ((size_t)mr*1024 + h0)*1024 + d0;
#pragma unroll
    for(int q=0;q<4;q++){
      int hr = q*16 + rr;
      bf16x4 o;
      o[0]=(__bf16)T[cc][hr];   o[1]=(__bf16)T[cc+1][hr];
      o[2]=(__bf16)T[cc+2][hr]; o[3]=(__bf16)T[cc+3][hr];
      *(bf16x4*)(dst + (size_t)hr*1024 + cc) = o;
    }
    return;
  }
  // ---- gate-others features ----
  {
    int row = b - 16384;
    int bb_ = row/3; int j = row - bb_*3; int oj = (j==0)?0:(j+1);
    if(tid==0) gpre[row]=0.f;
    const float* to=tokens+((size_t)bb_*4+oj)*HH;
    const float* ta=tokens+((size_t)bb_*4+1)*HH;
    float mo = mask[bb_*4+oj]?1.f:0.f;
    float* sc = &T[0][0];
    float ov[4], av[4], dv[4]; float s=0.f,s2=0.f;
#pragma unroll
    for(int p=0;p<4;p++){
      int h=tid+p*256;
      float o=to[h]*mo, a=ta[h], d=fabsf(o-a);
      ov[p]=o; av[p]=a; dv[p]=d;
      s+=o+a+d; s2+=o*o+a*a+d*d;
    }
    s=blockSum256(s,sc); s2=blockSum256(s2,sc);
    float mean=s/(float)D3, rstd=rsqrtf(s2/(float)D3-mean*mean+1e-5f);
    __bf16* fr = featGo + (size_t)row*D3;
#pragma unroll
    for(int p=0;p<4;p++){
      int h=tid+p*256;
      fr[h]       =(__bf16)((ov[p]-mean)*rstd*lnw[h]+lnb[h]);
      fr[1024+h]  =(__bf16)((av[p]-mean)*rstd*lnw[1024+h]+lnb[1024+h]);
      fr[2048+h]  =(__bf16)((dv[p]-mean)*rstd*lnw[2048+h]+lnb[2048+h]);
      if(j==0) audioB[(size_t)bb_*HH+h]=(__bf16)av[p];
    }
  }
}

// ================= dual-descriptor bf16 MFMA NT GEMM ========================
// act=0: C=A@B^T. act=1: C=gelu(A@B^T+bias). act=2: atomic gate-dot into gpre.
// 64x128 tile, BK=32, 4 waves, 3-buf depth-2 counted-vmcnt(3), XCD swizzle.
struct GD {
  const __bf16* A; const __bf16* B;
  const float* bias; float* C;
  const float* w2; float* gpre;
  int lda, ldb, ldc, K, nbx, nby, act;
};

__launch_bounds__(256, 4)
__global__ void gemm_dual_k(GD d0, GD d1, int n0){
  __shared__ __align__(16) __bf16 As[3*2048];
  __shared__ __align__(16) __bf16 Bs[3*4096];
  const int tid=threadIdx.x, l=tid&63, w=tid>>6;
  const int wr=w>>1, wc=w&1;
  const int quad=l>>4, lr16=l&15;

  GD d; int lb;
  if((int)blockIdx.x < n0){ d = d0; lb = blockIdx.x; }
  else                    { d = d1; lb = blockIdx.x - n0; }

  // XCD swizzle within segment (segment size always %8==0 here)
  const int chunk = (d.nbx*d.nby)>>3;
  const int nid = (lb&7)*chunk + (lb>>3);
  const int bx = nid % d.nbx, by = nid / d.nbx;
  const int row0=by*64, col0=bx*128;

  const int srow=l>>2, sq=(l&3)^((l>>3)&3);
  const int nsteps = d.K>>5;

  const __bf16* pa  = d.A + (size_t)(row0 + w*16       + srow)*d.lda + sq*8;
  const __bf16* pb0 = d.B + (size_t)(col0 + w*16       + srow)*d.ldb + sq*8;
  const __bf16* pb1 = d.B + (size_t)(col0 + (w+4)*16   + srow)*d.ldb + sq*8;
  __bf16* da  = As + ((size_t)w*64     + l)*8;
  __bf16* db0 = Bs + ((size_t)w*64     + l)*8;
  __bf16* db1 = Bs + ((size_t)(w+4)*64 + l)*8;

  auto stage=[&](int s,int bi){
    int k0 = s*32;
    gl_lds16(pa  + k0, da  + bi*2048);
    gl_lds16(pb0 + k0, db0 + bi*4096);
    gl_lds16(pb1 + k0, db1 + bi*4096);
  };

  f32x4 acc[2][4];
  f32x4 zerov={0.f,0.f,0.f,0.f};
#pragma unroll
  for(int i=0;i<2;i++)
#pragma unroll
    for(int j=0;j<4;j++) acc[i][j]=zerov;

  stage(0,0);
  stage(1,1);
  asm volatile("s_waitcnt vmcnt(3)" ::: "memory");
  __builtin_amdgcn_s_barrier();

  int cur=0;
  for(int step=0; step<nsteps; ++step){
    const __bf16* Ab = As + cur*2048;
    const __bf16* Bb = Bs + cur*4096;
    bf16x8 af[2], bg[4];
#pragma unroll
    for(int fi=0;fi<2;fi++){
      int R = wr*32 + fi*16 + lr16;
      af[fi]=*(const bf16x8*)(Ab + R*32 + ((quad^(R>>1))&3)*8);
    }
#pragma unroll
    for(int fj=0;fj<4;fj++){
      int N = wc*64 + fj*16 + lr16;
      bg[fj]=*(const bf16x8*)(Bb + N*32 + ((quad^(N>>1))&3)*8);
    }
    if(step+2<nsteps){
      int bi = cur + 2; if(bi>=3) bi-=3;
      stage(step+2, bi);
    }
    __builtin_amdgcn_s_setprio(1);
#pragma unroll
    for(int fi=0;fi<2;fi++)
#pragma unroll
      for(int fj=0;fj<4;fj++)
        acc[fi][fj]=__builtin_amdgcn_mfma_f32_16x16x32_bf16(af[fi],bg[fj],acc[fi][fj],0,0,0);
    __builtin_amdgcn_s_setprio(0);
    asm volatile("s_waitcnt lgkmcnt(0)" ::: "memory");
    if(step < nsteps-2) asm volatile("s_waitcnt vmcnt(3)" ::: "memory");
    else                asm volatile("s_waitcnt vmcnt(0)" ::: "memory");
    __builtin_amdgcn_s_barrier();
    cur = (cur+1==3)?0:cur+1;
  }

  if(d.act==2){
    float b1v[4], w2v[4];
#pragma unroll
    for(int fj=0;fj<4;fj++){
      int col=col0+wc*64+fj*16+lr16;
      b1v[fj]=d.bias[col]; w2v[fj]=d.w2[col];
    }
#pragma unroll
    for(int fi=0;fi<2;fi++){
#pragma unroll
      for(int reg=0;reg<4;reg++){
        float part=0.f;
#pragma unroll
        for(int fj=0;fj<4;fj++) part += gelu_f(acc[fi][fj][reg]+b1v[fj])*w2v[fj];
        part += __shfl_xor(part,1,64);
        part += __shfl_xor(part,2,64);
        part += __shfl_xor(part,4,64);
        part += __shfl_xor(part,8,64);
        if((l&15)==0) atomicAdd(&d.gpre[row0+wr*32+fi*16+quad*4+reg], part);
      }
    }
    return;
  }

  float bv[4];
#pragma unroll
  for(int fj=0;fj<4;fj++) bv[fj] = (d.act==1)? d.bias[col0+wc*64+fj*16+lr16] : 0.f;
#pragma unroll
  for(int fi=0;fi<2;fi++){
#pragma unroll
    for(int reg=0;reg<4;reg++){
      int row=row0+wr*32+fi*16+quad*4+reg;
#pragma unroll
      for(int fj=0;fj<4;fj++){
        int col=col0+wc*64+fj*16+lr16;
        float v=acc[fi][fj][reg];
        if(d.act==1) v=gelu_f(v+bv[fj]);
        d.C[(size_t)row*d.ldc+col]=v;
      }
    }
  }
}

// ------- others_new (mixedB 0,2,3) + omeanB + fused feat_ga + ga_pre=0 ------
__global__ void others_k(const float* __restrict__ tokens, const int* __restrict__ mask,
                         const float* __restrict__ gpre, const float* __restrict__ go_b2,
                         const float* __restrict__ a2o,
                         const float* __restrict__ lnw, const float* __restrict__ lnb,
                         const float* __restrict__ galnw, const float* __restrict__ galnb,
                         __bf16* __restrict__ mixedB, __bf16* __restrict__ omeanB,
                         __bf16* __restrict__ featGa, float* __restrict__ gapre){
  int b=blockIdx.x, tid=threadIdx.x;
  __shared__ float sc[4];
  if(tid==0) gapre[b]=0.f;
  float ma = mask[b*4+1]?1.f:0.f;
  float a2[4];
#pragma unroll
  for(int p=0;p<4;p++) a2[p]=a2o[(size_t)b*HH+tid+p*256];
  float sum[4]={0,0,0,0}; float cnt=0.f;
  for(int j=0;j<3;j++){
    int oj=(j==0)?0:(j+1);
    float mo=mask[b*4+oj]?1.f:0.f; cnt+=mo;
    float gv=1.f/(1.f+expf(-(gpre[b*3+j]+go_b2[0])));
    float t[4], ov[4]; float s=0.f,s2=0.f;
#pragma unroll
    for(int p=0;p<4;p++){
      int h=tid+p*256;
      float o=tokens[((size_t)b*4+oj)*HH+h]*mo;
      ov[p]=o; t[p]=o+gv*a2[p];
      s+=t[p]; s2+=t[p]*t[p];
    }
    s=blockSum256(s,sc); s2=blockSum256(s2,sc);
    float mean=s/1024.f, rstd=rsqrtf(s2/1024.f-mean*mean+1e-5f);
    float pv=mo*ma;
#pragma unroll
    for(int p=0;p<4;p++){
      int h=tid+p*256;
      float upd=(t[p]-mean)*rstd*lnw[h]+lnb[h];
      float on=((pv>0.5f)?upd:ov[p])*mo;
      mixedB[(size_t)b*4096 + (size_t)oj*HH + h]=(__bf16)on;
      sum[p]+=on*mo;
    }
  }
  float denom=fmaxf(cnt,1.f);
  float vm[4];
#pragma unroll
  for(int p=0;p<4;p++){
    vm[p]=sum[p]/denom;
    omeanB[(size_t)b*HH+tid+p*256]=(__bf16)vm[p];
  }
  // ---- fused gate-audio features: LN([audio, omean, |diff|]) ----
  const float* ta=tokens+((size_t)b*4+1)*HH;
  float tv[4], dv[4]; float s=0.f,s2=0.f;
#pragma unroll
  for(int p=0;p<4;p++){
    int h=tid+p*256;
    float a=ta[h], d=fabsf(a-vm[p]);
    tv[p]=a; dv[p]=d;
    s+=a+vm[p]+d; s2+=a*a+vm[p]*vm[p]+d*d;
  }
  s=blockSum256(s,sc); s2=blockSum256(s2,sc);
  float mean=s/(float)D3, rstd=rsqrtf(s2/(float)D3-mean*mean+1e-5f);
  __bf16* fr=featGa+(size_t)b*D3;
#pragma unroll
  for(int p=0;p<4;p++){
    int h=tid+p*256;
    fr[h]     =(__bf16)((tv[p]-mean)*rstd*galnw[h]+galnb[h]);
    fr[1024+h]=(__bf16)((vm[p]-mean)*rstd*galnw[1024+h]+galnb[1024+h]);
    fr[2048+h]=(__bf16)((dv[p]-mean)*rstd*galnw[2048+h]+galnb[2048+h]);
  }
}

// ------- mixed_audio (mixedB slot 1) + fused init to lmf_bias ---------------
__global__ void audio_k(const float* __restrict__ tokens, const int* __restrict__ mask,
                        const float* __restrict__ gapre, const float* __restrict__ ga_b2,
                        const float* __restrict__ o2a,
                        const float* __restrict__ lnw, const float* __restrict__ lnb,
                        __bf16* __restrict__ mixedB,
                        const float* __restrict__ lmf_bias, float* __restrict__ fused){
  int b=blockIdx.x, tid=threadIdx.x;
  __shared__ float sc[4];
  int ma_i=mask[b*4+1];
  int any = mask[b*4+0]|mask[b*4+2]|mask[b*4+3];
  bool aum = (ma_i!=0) && (any!=0);
  float ma = ma_i?1.f:0.f;
  float gv=1.f/(1.f+expf(-(gapre[b]+ga_b2[0])));
  const float* ta = tokens + ((size_t)b*4+1)*HH;
  float av[4], t[4]; float s=0.f,s2=0.f;
#pragma unroll
  for(int p=0;p<4;p++){
    int h=tid+p*256;
    av[p]=ta[h];
    t[p]=av[p]+gv*o2a[(size_t)b*HH+h];
    s+=t[p]; s2+=t[p]*t[p];
  }
  s=blockSum256(s,sc); s2=blockSum256(s2,sc);
  float mean=s/1024.f, rstd=rsqrtf(s2/1024.f-mean*mean+1e-5f);
#pragma unroll
  for(int p=0;p<4;p++){
    int h=tid+p*256;
    float u=(t[p]-mean)*rstd*lnw[h]+lnb[h];
    float outv = aum ? u : av[p]*ma;
    mixedB[(size_t)b*4096 + HH + h]=(__bf16)(outv*ma);
    fused[(size_t)b*HH + h]=lmf_bias[h];
  }
}

// -------- LMF: fused[b,h] += sum_{r in half} rank_w[r]*prod_m(mask? z : 1) --
// r INSIDE the block; no P buffer. 128x128 tile, 640 K-steps, 3-buf pipeline.
// XCD swizzle: XCD x owns {bz=x&1, by-group x>>1 (8 rows), all 8 hh} ->
// per-phase resident = 8 A-tiles (2MB) + 8 B-slices (2MB) = 4MB L2, both shared.
__launch_bounds__(256, 2)
__global__ void gemm_lmf2(const __bf16* __restrict__ mixedB,
                          const __bf16* __restrict__ factT,
                          const float* __restrict__ factors,
                          const int* __restrict__ mask,
                          const float* __restrict__ rank_w,
                          float* __restrict__ fused){
  __shared__ __align__(16) __bf16 As[3*4096];
  __shared__ __align__(16) __bf16 Bs[3*4096];
  __shared__ float Mskf[4][128];
  __shared__ float F0s[20][128];
  __shared__ float Rws[5];
  const int tid = threadIdx.x;
  const int l = tid & 63, w = tid >> 6;
  const int wr = w >> 1, wc = w & 1;
  const int quad = l >> 4, lr16 = l & 15;

  const int flat = blockIdx.x + 8*(blockIdx.y + 32*blockIdx.z);
  const int x    = flat & 7;         // XCD
  const int j    = flat >> 3;        // 0..63 within XCD
  const int bz   = x & 1;
  const int by   = (x >> 1)*8 + (j >> 3);
  const int hh   = j & 7;
  const int row0 = by * 128, col0 = hh * 128;
  const int z5   = bz * 5;

  const int srow = l >> 2;
  const int sq   = (l & 3) ^ ((l >> 3) & 3);

  // ---- prologue: masks + F0 rows + rank_w into LDS ----
  for(int i = tid; i < 512; i += 256){
    int mm = i >> 7, rl = i & 127;
    Mskf[mm][rl] = mask[(row0 + rl)*4 + mm] ? 1.f : 0.f;
  }
  for(int i = tid; i < 2560; i += 256){
    int rm = i >> 7, cl = i & 127;
    int m = rm & 3, rg = z5 + (rm >> 2);
    F0s[rm][cl] = factors[(size_t)(m*RR + rg)*1025*1024 + col0 + cl];
  }
  if(tid < 5) Rws[tid] = rank_w[z5 + tid];

  const __bf16* pa0 = mixedB + (size_t)(row0 + w*16     + srow)*4096 + sq*8;
  const __bf16* pa1 = mixedB + (size_t)(row0 + (w+4)*16 + srow)*4096 + sq*8;
  const __bf16* pb0 = factT + ((size_t)(col0 + w*16     + srow))*1024 + sq*8;
  const __bf16* pb1 = factT + ((size_t)(col0 + (w+4)*16 + srow))*1024 + sq*8;
  __bf16* da0 = As + ((size_t)w*64     + l)*8;
  __bf16* da1 = As + ((size_t)(w+4)*64 + l)*8;
  __bf16* db0 = Bs + ((size_t)w*64     + l)*8;
  __bf16* db1 = Bs + ((size_t)(w+4)*64 + l)*8;

  auto stage = [&](int s, int bi){
    int rm = s >> 5, k0 = (s & 31)*32;
    int m = rm & 3, rg = z5 + (rm >> 2);
    size_t ao = (size_t)m*1024 + k0;
    size_t bo = (size_t)(m*RR + rg)*1048576 + k0;
    gl_lds16(pa0 + ao, da0 + bi*4096);
    gl_lds16(pa1 + ao, da1 + bi*4096);
    gl_lds16(pb0 + bo, db0 + bi*4096);
    gl_lds16(pb1 + bo, db1 + bi*4096);
  };

  f32x4 fsum[4][4];
  f32x4 prod[4][4];
  f32x4 acc[4][4];
  f32x4 zerov = {0.f,0.f,0.f,0.f};
#pragma unroll
  for(int i=0;i<4;i++)
#pragma unroll
    for(int j2=0;j2<4;j2++) fsum[i][j2] = zerov;

  stage(0, 0);
  stage(1, 1);
  asm volatile("s_waitcnt vmcnt(4)" ::: "memory");
  asm volatile("s_waitcnt lgkmcnt(0)" ::: "memory");
  __builtin_amdgcn_s_barrier();

  int cur = 0;
  for(int step = 0; step < 640; ++step){
    const __bf16* Ab = As + cur*4096;
    const __bf16* Bb = Bs + cur*4096;
    bf16x8 af[4], bg[4];
#pragma unroll
    for(int fi=0;fi<4;fi++){
      int R = wr*64 + fi*16 + lr16;
      af[fi] = *(const bf16x8*)(Ab + R*32 + ((quad ^ (R>>1)) & 3)*8);
    }
#pragma unroll
    for(int fj=0;fj<4;fj++){
      int N = wc*64 + fj*16 + lr16;
      bg[fj] = *(const bf16x8*)(Bb + N*32 + ((quad ^ (N>>1)) & 3)*8);
    }
    if(step + 2 < 640){
      int bi = cur + 2; if(bi >= 3) bi -= 3;
      stage(step + 2, bi);
    }
    if((step & 127) == 0){
      f32x4 onev = {1.f,1.f,1.f,1.f};
#pragma unroll
      for(int fi=0;fi<4;fi++)
#pragma unroll
        for(int fj=0;fj<4;fj++) prod[fi][fj] = onev;
    }
    if((step & 31) == 0){
      int rm = step >> 5;
#pragma unroll
      for(int fj=0;fj<4;fj++){
        float f0 = F0s[rm][wc*64 + fj*16 + lr16];
        f32x4 iv = {f0,f0,f0,f0};
#pragma unroll
        for(int fi=0;fi<4;fi++) acc[fi][fj] = iv;
      }
    }
    __builtin_amdgcn_s_setprio(1);
#pragma unroll
    for(int fi=0;fi<4;fi++)
#pragma unroll
      for(int fj=0;fj<4;fj++)
        acc[fi][fj] = __builtin_amdgcn_mfma_f32_16x16x32_bf16(af[fi], bg[fj], acc[fi][fj], 0,0,0);
    __builtin_amdgcn_s_setprio(0);
    if((step & 31) == 31){
      int mm = (step >> 5) & 3;
#pragma unroll
      for(int fi=0;fi<4;fi++)
#pragma unroll
        for(int reg=0;reg<4;reg++){
          float mk = Mskf[mm][wr*64 + fi*16 + quad*4 + reg];
#pragma unroll
          for(int fj=0;fj<4;fj++)
            prod[fi][fj][reg] *= (mk != 0.f) ? acc[fi][fj][reg] : 1.f;
        }
    }
    if((step & 127) == 127){
      float rw = Rws[step >> 7];
#pragma unroll
      for(int fi=0;fi<4;fi++)
#pragma unroll
        for(int fj=0;fj<4;fj++)
#pragma unroll
          for(int reg=0;reg<4;reg++)
            fsum[fi][fj][reg] += rw * prod[fi][fj][reg];
    }
    asm volatile("s_waitcnt lgkmcnt(0)" ::: "memory");
    if(step < 638) asm volatile("s_waitcnt vmcnt(4)" ::: "memory");
    else           asm volatile("s_waitcnt vmcnt(0)" ::: "memory");
    __builtin_amdgcn_s_barrier();
    cur = (cur + 1 == 3) ? 0 : cur + 1;
  }

#pragma unroll
  for(int fi=0;fi<4;fi++){
#pragma unroll
    for(int reg=0;reg<4;reg++){
      int row = row0 + wr*64 + fi*16 + quad*4 + reg;
#pragma unroll
      for(int fj=0;fj<4;fj++){
        int col = col0 + wc*64 + fj*16 + lr16;
        atomicAdd(&fused[(size_t)row*HH + col], fsum[fi][fj][reg]);
      }
    }
  }
}

// ---------------- row LayerNorm over H=1024 (fp32 out) ----------------------
__global__ void ln_row_k(const float* __restrict__ X, const float* __restrict__ w,
                         const float* __restrict__ bb, float* __restrict__ Y){
  int b=blockIdx.x, tid=threadIdx.x;
  __shared__ float sc[4];
  const float* x=X+(size_t)b*HH;
  float t[4]; float s=0.f,s2=0.f;
#pragma unroll
  for(int p=0;p<4;p++){ t[p]=x[tid+p*256]; s+=t[p]; s2+=t[p]*t[p]; }
  s=blockSum256(s,sc); s2=blockSum256(s2,sc);
  float mean=s/1024.f, rstd=rsqrtf(s2/1024.f-mean*mean+1e-5f);
#pragma unroll
  for(int p=0;p<4;p++){
    int h=tid+p*256;
    Y[(size_t)b*HH+h]=(t[p]-mean)*rstd*w[h]+bb[h];
  }
}
// ---------------- row LayerNorm over H=1024 (bf16 out) ----------------------
__global__ void ln_row_bf16_k(const float* __restrict__ X, const float* __restrict__ w,
                              const float* __restrict__ bb, __bf16* __restrict__ Y){
  int b=blockIdx.x, tid=threadIdx.x;
  __shared__ float sc[4];
  const float* x=X+(size_t)b*HH;
  float t[4]; float s=0.f,s2=0.f;
#pragma unroll
  for(int p=0;p<4;p++){ t[p]=x[tid+p*256]; s+=t[p]; s2+=t[p]*t[p]; }
  s=blockSum256(s,sc); s2=blockSum256(s2,sc);
  float mean=s/1024.f, rstd=rsqrtf(s2/1024.f-mean*mean+1e-5f);
#pragma unroll
  for(int p=0;p<4;p++){
    int h=tid+p*256;
    Y[(size_t)b*HH+h]=(__bf16)((t[p]-mean)*rstd*w[h]+bb[h]);
  }
}

// ---------------- launch ----------------------------------------------------
extern "C" void kernel_launch(void* const* d_in, const int* in_sizes, int n_in,
                              void* d_out, int out_size, void* d_ws, size_t ws_size,
                              hipStream_t stream) {
  const float* tokens   =(const float*)d_in[0];
  const int*   mask     =(const int*)  d_in[1];
  const float* ln_go_w  =(const float*)d_in[2];
  const float* ln_go_b  =(const float*)d_in[3];
  const float* go_w1    =(const float*)d_in[4];
  const float* go_b1    =(const float*)d_in[5];
  const float* go_w2    =(const float*)d_in[6];
  const float* go_b2    =(const float*)d_in[7];
  const float* ln_ga_w  =(const float*)d_in[8];
  const float* ln_ga_b  =(const float*)d_in[9];
  const float* ga_w1    =(const float*)d_in[10];
  const float* ga_b1    =(const float*)d_in[11];
  const float* ga_w2    =(const float*)d_in[12];
  const float* ga_b2    =(const float*)d_in[13];
  const float* a2o_w    =(const float*)d_in[14];
  const float* o2a_w    =(const float*)d_in[15];
  const float* ln_o_w   =(const float*)d_in[16];
  const float* ln_o_b   =(const float*)d_in[17];
  const float* ln_a_w   =(const float*)d_in[18];
  const float* ln_a_b   =(const float*)d_in[19];
  const float* factors  =(const float*)d_in[20];
  const float* rank_w   =(const float*)d_in[21];
  const float* lmf_bias =(const float*)d_in[22];
  const float* out_ln1_w=(const float*)d_in[23];
  const float* out_ln1_b=(const float*)d_in[24];
  const float* out_w    =(const float*)d_in[25];
  const float* out_b    =(const float*)d_in[26];
  const float* out_ln2_w=(const float*)d_in[27];
  const float* out_ln2_b=(const float*)d_in[28];
  float* out=(float*)d_out;

  char* wsp=(char*)d_ws; size_t off=0;
  auto alloc=[&](size_t bytes)->void*{
    void* p=wsp+off; off=(off+bytes+255)&~(size_t)255; return p;
  };
  __bf16* factT   =(__bf16*)alloc((size_t)4*RR*HH*HH*2);    // 84 MB
  __bf16* featGo  =(__bf16*)alloc((size_t)BB*3*D3*2);       // 75.5 MB
  __bf16* featGa  =(__bf16*)alloc((size_t)BB*D3*2);         // 25.2 MB
  float*  g_go_pre=(float*) alloc((size_t)BB*3*4);
  float*  ga_pre  =(float*) alloc((size_t)BB*4);
  float*  a2o     =(float*) alloc((size_t)BB*HH*4);
  __bf16* mixedB  =(__bf16*)alloc((size_t)BB*4*HH*2);
  __bf16* omeanB  =(__bf16*)alloc((size_t)BB*HH*2);
  __bf16* audioB  =(__bf16*)alloc((size_t)BB*HH*2);
  float*  o2a     =(float*) alloc((size_t)BB*HH*4);
  float*  fused   =(float*) alloc((size_t)BB*HH*4);
  __bf16* hbufB   =(__bf16*)alloc((size_t)BB*HH*2);
  __bf16* go_w1B  =(__bf16*)alloc((size_t)MIDD*D3*2);
  __bf16* ga_w1B  =(__bf16*)alloc((size_t)MIDD*D3*2);
  __bf16* a2o_wB  =(__bf16*)alloc((size_t)HH*HH*2);
  __bf16* o2a_wB  =(__bf16*)alloc((size_t)HH*HH*2);
  __bf16* out_wB  =(__bf16*)alloc((size_t)HH*HH*2);

  // 1) prep: weight converts + factor transpose + gate-others features
  prep_k<<<28672,256,0,stream>>>(go_w1,go_w1B, ga_w1,ga_w1B, a2o_w,a2o_wB,
                                 o2a_w,o2a_wB, out_w,out_wB,
                                 factors,factT,
                                 tokens,mask,ln_go_w,ln_go_b,featGo,audioB,g_go_pre);
  // 2) a2o GEMM || gate-others MLP (atomic)  — one launch
  {
    GD dA = { audioB, a2o_wB, nullptr, a2o, nullptr, nullptr,
              HH, HH, HH, HH, 8, 64, 0 };
    GD dH = { featGo, go_w1B, go_b1, nullptr, go_w2, g_go_pre,
              D3, D3, 0, D3, 4, 192, 2 };
    gemm_dual_k<<<512+768,256,0,stream>>>(dA, dH, 512);
  }
  // 3) others_new + omeanB + featGa + ga_pre=0
  others_k<<<BB,256,0,stream>>>(tokens,mask,g_go_pre,go_b2,a2o,ln_o_w,ln_o_b,
                                ln_ga_w,ln_ga_b,mixedB,omeanB,featGa,ga_pre);
  // 4) gate-audio MLP (atomic) || o2a GEMM — one launch
  {
    GD dH = { featGa, ga_w1B, ga_b1, nullptr, ga_w2, ga_pre,
              D3, D3, 0, D3, 4, 64, 2 };
    GD dO = { omeanB, o2a_wB, nullptr, o2a, nullptr, nullptr,
              HH, HH, HH, HH, 8, 64, 0 };
    gemm_dual_k<<<256+512,256,0,stream>>>(dH, dO, 256);
  }
  // 5) mixed_audio -> mixedB slot 1; fused init to lmf_bias
  audio_k<<<BB,256,0,stream>>>(tokens,mask,ga_pre,ga_b2,o2a,ln_a_w,ln_a_b,mixedB,lmf_bias,fused);
  // 6) LMF: r-inside, atomic accumulate into fused (no P buffer)
  gemm_lmf2<<<dim3(8,32,2),256,0,stream>>>(mixedB,factT,factors,mask,rank_w,fused);
  // 7) hbufB = LN(fused) as bf16
  ln_row_bf16_k<<<BB,256,0,stream>>>(fused,out_ln1_w,out_ln1_b,hbufB);
  // 8) fused = gelu(hbufB @ out_w^T + out_b)
  {
    GD dO = { hbufB, out_wB, out_b, fused, nullptr, nullptr,
              HH, HH, HH, HH, 8, 64, 1 };
    gemm_dual_k<<<512,256,0,stream>>>(dO, dO, 512);
  }
  // 9) out = LN(fused)
  ln_row_k<<<BB,256,0,stream>>>(fused,out_ln2_w,out_ln2_b,out);
}